// Round 11
// baseline (989.396 us; speedup 1.0000x reference)
//
#include <hip/hip_runtime.h>
#include <hip/hip_bf16.h>
#include <math.h>

// Problem constants
#define NN 100000
#define EE 1600000
#define FIN 20
#define HH 128
#define NBUK 391         // ceil(NN/256) buckets of 256 nodes
#define FILLB 196        // ceil(EE/8192) fill blocks
#define MMB 782          // ceil(NN/128) GEMM row-tiles

typedef __attribute__((ext_vector_type(8))) short bf16x8;
typedef __attribute__((ext_vector_type(4))) float f32x4;

__device__ __forceinline__ unsigned short f2b(float x) {
    unsigned int b = __float_as_uint(x);
    unsigned int r = b + 0x7fffu + ((b >> 16) & 1u);
    return (unsigned short)(r >> 16);
}
__device__ __forceinline__ float lof(unsigned int u) { return __uint_as_float(u << 16); }
__device__ __forceinline__ float hif(unsigned int u) { return __uint_as_float(u & 0xffff0000u); }
__device__ __forceinline__ unsigned int pk2(float a, float b) {
    return (unsigned int)f2b(a) | ((unsigned int)f2b(b) << 16);
}

__device__ __forceinline__ float gelu_exact(float z) {
    return 0.5f * z * (1.0f + erff(z * 0.70710678118654752f));
}

// ---------------------------------------------------------------------------
// CSR build via bucketed binning
// ---------------------------------------------------------------------------
__global__ __launch_bounds__(256) void kb_cnt(const int* __restrict__ dst,
                                              int* __restrict__ bcnt) {
    __shared__ int c[NBUK];
    int t = threadIdx.x;
    for (int i = t; i < NBUK; i += 256) c[i] = 0;
    __syncthreads();
    int e0 = blockIdx.x * 8192;
    #pragma unroll 4
    for (int i = 0; i < 32; ++i) {
        int e = e0 + i * 256 + t;
        if (e < EE) atomicAdd(&c[dst[e] >> 8], 1);
    }
    __syncthreads();
    for (int i = t; i < NBUK; i += 256) if (c[i]) atomicAdd(&bcnt[i], c[i]);
}

__global__ void kb_scan(const int* __restrict__ bcnt, int* __restrict__ bbase,
                        int* __restrict__ cursor) {
    __shared__ int sh[512];
    int t = threadIdx.x;
    int v = (t < NBUK) ? bcnt[t] : 0;
    sh[t] = v;
    __syncthreads();
    for (int off = 1; off < 512; off <<= 1) {
        int add = (t >= off) ? sh[t - off] : 0;
        __syncthreads();
        sh[t] += add;
        __syncthreads();
    }
    if (t < NBUK) {
        int ex = sh[t] - v;
        bbase[t] = ex;
        cursor[t] = ex;
    }
    if (t == NBUK - 1) bbase[NBUK] = sh[t];
}

__global__ __launch_bounds__(256) void kb_fill(const int* __restrict__ src,
        const int* __restrict__ dst, int* __restrict__ cursor,
        unsigned int* __restrict__ pairs) {
    __shared__ int cnt[NBUK], base[NBUK], boff[NBUK];
    int t = threadIdx.x;
    for (int i = t; i < NBUK; i += 256) { cnt[i] = 0; boff[i] = 0; }
    __syncthreads();
    int e0 = blockIdx.x * 8192;
    #pragma unroll 4
    for (int i = 0; i < 32; ++i) {
        int e = e0 + i * 256 + t;
        if (e < EE) atomicAdd(&cnt[dst[e] >> 8], 1);
    }
    __syncthreads();
    for (int i = t; i < NBUK; i += 256)
        if (cnt[i]) base[i] = atomicAdd(&cursor[i], cnt[i]);
    __syncthreads();
    #pragma unroll 4
    for (int i = 0; i < 32; ++i) {
        int e = e0 + i * 256 + t;
        if (e < EE) {
            int d = dst[e];
            int b = d >> 8;
            int pos = base[b] + atomicAdd(&boff[b], 1);
            pairs[pos] = (unsigned int)src[e] | ((unsigned int)(d & 255) << 17);
        }
    }
}

__global__ __launch_bounds__(256) void kb_csr(const unsigned int* __restrict__ pairs,
        const int* __restrict__ bbase, int* __restrict__ row_start,
        int* __restrict__ deg, float* __restrict__ invdeg, int* __restrict__ col) {
    __shared__ int ldeg[256];
    __shared__ int lcnt[256];
    int b = blockIdx.x, t = threadIdx.x;
    int e0 = bbase[b], e1 = bbase[b + 1];
    ldeg[t] = 0;
    lcnt[t] = 0;
    __syncthreads();
    for (int e = e0 + t; e < e1; e += 256) atomicAdd(&ldeg[pairs[e] >> 17], 1);
    __syncthreads();
    int d = ldeg[t];
    for (int off = 1; off < 256; off <<= 1) {
        int add = (t >= off) ? ldeg[t - off] : 0;
        __syncthreads();
        ldeg[t] += add;
        __syncthreads();
    }
    int n = b * 256 + t;
    if (n < NN) {
        row_start[n] = e0 + ldeg[t] - d;
        deg[n] = d;
        invdeg[n] = 1.0f / fmaxf((float)d, 1.0f);
    }
    __syncthreads();
    for (int e = e0 + t; e < e1; e += 256) {
        unsigned int p = pairs[e];
        int dL = p >> 17;
        int pos = e0 + (dL ? ldeg[dL - 1] : 0) + atomicAdd(&lcnt[dL], 1);
        col[pos] = (int)(p & 0x1FFFFu);
    }
}

// ---------------------------------------------------------------------------
// Mega-pack: xb, Wt0, Wt2a, Wt2b, W1b, W2b, biases, bcnt zero-init
// ---------------------------------------------------------------------------
#define XB_N  (NN * 32)
#define PACK_TOTAL (XB_N + 8192 + 32768 + 32768 + 8192 + 2048 + 64 + 32 + NBUK)
__global__ __launch_bounds__(256) void k_pack_all(const float* __restrict__ x,
        const float* __restrict__ Wl0, const float* __restrict__ Wr0,
        const float* __restrict__ Wl1, const float* __restrict__ Wr1,
        const float* __restrict__ Wl2, const float* __restrict__ Wr2,
        const float* __restrict__ hW1, const float* __restrict__ hW2,
        const float* __restrict__ hb1, const float* __restrict__ hb2,
        unsigned short* __restrict__ xb,
        unsigned short* __restrict__ Wt0, unsigned short* __restrict__ Wt2a,
        unsigned short* __restrict__ Wt2b, unsigned short* __restrict__ W1b,
        unsigned short* __restrict__ W2b, float* __restrict__ bH1,
        float* __restrict__ bH2, int* __restrict__ bcnt) {
    int id = blockIdx.x * 256 + threadIdx.x;
    if (id < XB_N) {
        int n = id >> 5, k = id & 31;
        xb[id] = f2b((k < FIN) ? x[n * FIN + k] : 0.0f);
        return;
    }
    id -= XB_N;
    if (id < 8192) {  // Wt0: 128 x 64  [Wl0(20)|0|Wr0(20)|0]
        int c = id >> 6, k = id & 63;
        float v = 0.0f;
        if (k < FIN) v = Wl0[c * FIN + k];
        else if (k >= 32 && k < 32 + FIN) v = Wr0[c * FIN + (k - 32)];
        Wt0[id] = f2b(v);
        return;
    }
    id -= 8192;
    if (id < 32768) {  // layer-1 weights 128 x 256
        int c = id >> 8, k = id & 255;
        Wt2a[id] = f2b((k < HH) ? Wl1[c * HH + k] : Wr1[c * HH + (k - HH)]);
        return;
    }
    id -= 32768;
    if (id < 32768) {  // layer-2 weights
        int c = id >> 8, k = id & 255;
        Wt2b[id] = f2b((k < HH) ? Wl2[c * HH + k] : Wr2[c * HH + (k - HH)]);
        return;
    }
    id -= 32768;
    if (id < 8192) { W1b[id] = f2b(hW1[id]); return; }   // 64 x 128
    id -= 8192;
    if (id < 2048) { W2b[id] = f2b(hW2[id]); return; }   // 32 x 64
    id -= 2048;
    if (id < 64) { bH1[id] = hb1[id]; return; }
    id -= 64;
    if (id < 32) { bH2[id] = hb2[id]; return; }
    id -= 32;
    if (id < NBUK) { bcnt[id] = 0; return; }
}

// ---------------------------------------------------------------------------
// Layer 0 fused: per-block gather (xb 64 B rows) + x-copy into LDS A-tile,
// then K=64 MFMA GEMM with fused GraphNorm partial stats.
// ---------------------------------------------------------------------------
__global__ __launch_bounds__(256) void k_mm0(const uint2* __restrict__ xb2,
        const int* __restrict__ rs, const int* __restrict__ deg,
        const float* __restrict__ inv, const int* __restrict__ col,
        const unsigned short* __restrict__ B, const float* __restrict__ bias,
        unsigned short* __restrict__ outB, float* __restrict__ psPart,
        float* __restrict__ pqPart, int M) {
    __shared__ __align__(16) unsigned short Ag[128 * 72];  // K=64, stride 72
    __shared__ __align__(16) unsigned short Bs[128 * 40];
    __shared__ float redS[2][128], redQ[2][128];
    const int tid = threadIdx.x;
    const int m0 = blockIdx.x * 128;
    const int w = tid >> 6, lane = tid & 63;
    const int wr = w >> 1, wc = w & 1;
    const int m16 = lane & 15, q = lane >> 4;
    const int er = lane >> 3, c8 = lane & 7;

    // Phase A: gather + x-copy. Wave w handles local nodes w, w+4, ...
    for (int nn = w; nn < 128; nn += 4) {
        int n = m0 + nn;
        float a0 = 0.f, a1 = 0.f, a2 = 0.f, a3 = 0.f;
        if (n < M) {
            int s = rs[n], d = deg[n];
            for (int j0 = 0; j0 < d; j0 += 8) {
                int j = j0 + er;
                if (j < d) {
                    int c = col[s + j];
                    uint2 v = xb2[(size_t)c * 8 + c8];
                    a0 += lof(v.x); a1 += hif(v.x);
                    a2 += lof(v.y); a3 += hif(v.y);
                }
            }
            #pragma unroll
            for (int m = 8; m < 64; m <<= 1) {
                a0 += __shfl_xor(a0, m, 64);
                a1 += __shfl_xor(a1, m, 64);
                a2 += __shfl_xor(a2, m, 64);
                a3 += __shfl_xor(a3, m, 64);
            }
        }
        if (er == 0) {
            float iv = (n < M) ? inv[n] : 0.0f;
            uint2 o = make_uint2(0u, 0u);
            if (c8 < 5) { o.x = pk2(a0 * iv, a1 * iv); o.y = pk2(a2 * iv, a3 * iv); }
            *(uint2*)&Ag[nn * 72 + c8 * 4] = o;           // cols 0..31
        } else if (er == 1) {
            uint2 v = make_uint2(0u, 0u);
            if (n < M) v = xb2[(size_t)n * 8 + c8];
            *(uint2*)&Ag[nn * 72 + 32 + c8 * 4] = v;      // cols 32..63
        }
    }

    f32x4 acc[4][4];
    #pragma unroll
    for (int i = 0; i < 4; ++i)
        #pragma unroll
        for (int j = 0; j < 4; ++j) acc[i][j] = (f32x4){0.f, 0.f, 0.f, 0.f};

    for (int chunk = 0; chunk < 2; ++chunk) {
        const int kb = chunk * 32;
        #pragma unroll
        for (int it = 0; it < 2; ++it) {
            int s = tid + it * 256;
            int r = s >> 2, p = s & 3;
            uint4 v = *(const uint4*)(B + (size_t)r * 64 + kb + p * 8);
            *(uint4*)&Bs[r * 40 + p * 8] = v;
        }
        __syncthreads();
        bf16x8 af[4], bfr[4];
        #pragma unroll
        for (int i = 0; i < 4; ++i)
            af[i] = *(const bf16x8*)&Ag[(wr * 64 + i * 16 + m16) * 72 + kb + q * 8];
        #pragma unroll
        for (int j = 0; j < 4; ++j)
            bfr[j] = *(const bf16x8*)&Bs[(wc * 64 + j * 16 + m16) * 40 + q * 8];
        #pragma unroll
        for (int i = 0; i < 4; ++i)
            #pragma unroll
            for (int j = 0; j < 4; ++j)
                acc[i][j] = __builtin_amdgcn_mfma_f32_16x16x32_bf16(af[i], bfr[j], acc[i][j], 0, 0, 0);
        __syncthreads();
    }

    float cs[4] = {0.f, 0.f, 0.f, 0.f};
    float cq[4] = {0.f, 0.f, 0.f, 0.f};
    #pragma unroll
    for (int i = 0; i < 4; ++i) {
        int mBase = m0 + wr * 64 + i * 16 + q * 4;
        #pragma unroll
        for (int j = 0; j < 4; ++j) {
            int cc = wc * 64 + j * 16 + m16;
            float bv = bias[cc];
            #pragma unroll
            for (int r = 0; r < 4; ++r) {
                int m = mBase + r;
                float v = (m < M) ? (acc[i][j][r] + bv) : 0.0f;
                if (m < M) outB[(size_t)m * 128 + cc] = f2b(v);
                cs[j] += v;
                cq[j] += v * v;
            }
        }
    }
    #pragma unroll
    for (int msk = 16; msk < 64; msk <<= 1) {
        #pragma unroll
        for (int j = 0; j < 4; ++j) {
            cs[j] += __shfl_xor(cs[j], msk, 64);
            cq[j] += __shfl_xor(cq[j], msk, 64);
        }
    }
    if (q == 0) {
        #pragma unroll
        for (int j = 0; j < 4; ++j) {
            int cc = wc * 64 + j * 16 + m16;
            redS[wr][cc] = cs[j];
            redQ[wr][cc] = cq[j];
        }
    }
    __syncthreads();
    if (tid < 128) {
        psPart[(size_t)blockIdx.x * 128 + tid] = redS[0][tid] + redS[1][tid];
        pqPart[(size_t)blockIdx.x * 128 + tid] = redQ[0][tid] + redQ[1][tid];
    }
}

// ---------------------------------------------------------------------------
// Layers 1/2 fused: per-block gather of 128 nodes (h 256 B rows, wave-per-node,
// 8-edge unroll) into 34 KB LDS A-tile; K=256 MFMA (chunks 0-3 from agg tile,
// 4-7 staged from h); fused GraphNorm partial stats. 56 KB LDS -> 2 blocks/CU;
// gather blocks overlap MFMA blocks across the grid.
// ---------------------------------------------------------------------------
__global__ __launch_bounds__(256) void k_mmagg(const unsigned short* __restrict__ hB,
        const int* __restrict__ rs, const int* __restrict__ deg,
        const float* __restrict__ inv, const int* __restrict__ col,
        const unsigned short* __restrict__ B, const float* __restrict__ bias,
        unsigned short* __restrict__ outB, float* __restrict__ psPart,
        float* __restrict__ pqPart, int M) {
    __shared__ __align__(16) unsigned short Ag[128 * 136];  // agg tile K=128
    __shared__ __align__(16) unsigned short As[128 * 40];   // h-chunk staging
    __shared__ __align__(16) unsigned short Bs[128 * 40];
    __shared__ float redS[2][128], redQ[2][128];
    const int tid = threadIdx.x;
    const int m0 = blockIdx.x * 128;
    const int w = tid >> 6, lane = tid & 63;
    const int wr = w >> 1, wc = w & 1;
    const int m16 = lane & 15, q = lane >> 4;
    const unsigned int* h32 = (const unsigned int*)hB;

    // Phase A: gather. Wave w aggregates local nodes w, w+4, ..., 124.
    for (int nn = w; nn < 128; nn += 4) {
        int n = m0 + nn;
        float a0 = 0.0f, a1 = 0.0f;
        float iv = 0.0f;
        if (n < M) {
            int s = rs[n], d = deg[n];
            int j = 0;
            for (; j + 7 < d; j += 8) {
                int c0 = col[s + j],     c1 = col[s + j + 1];
                int c2 = col[s + j + 2], c3 = col[s + j + 3];
                int c4 = col[s + j + 4], c5 = col[s + j + 5];
                int c6 = col[s + j + 6], c7 = col[s + j + 7];
                unsigned int u0 = h32[(size_t)c0 * 64 + lane];
                unsigned int u1 = h32[(size_t)c1 * 64 + lane];
                unsigned int u2 = h32[(size_t)c2 * 64 + lane];
                unsigned int u3 = h32[(size_t)c3 * 64 + lane];
                unsigned int u4 = h32[(size_t)c4 * 64 + lane];
                unsigned int u5 = h32[(size_t)c5 * 64 + lane];
                unsigned int u6 = h32[(size_t)c6 * 64 + lane];
                unsigned int u7 = h32[(size_t)c7 * 64 + lane];
                a0 += lof(u0) + lof(u1) + lof(u2) + lof(u3)
                    + lof(u4) + lof(u5) + lof(u6) + lof(u7);
                a1 += hif(u0) + hif(u1) + hif(u2) + hif(u3)
                    + hif(u4) + hif(u5) + hif(u6) + hif(u7);
            }
            for (; j < d; ++j) {
                unsigned int u = h32[(size_t)col[s + j] * 64 + lane];
                a0 += lof(u);
                a1 += hif(u);
            }
            iv = inv[n];
        }
        *(unsigned int*)&Ag[nn * 136 + lane * 2] = pk2(a0 * iv, a1 * iv);
    }
    __syncthreads();

    f32x4 acc[4][4];
    #pragma unroll
    for (int i = 0; i < 4; ++i)
        #pragma unroll
        for (int j = 0; j < 4; ++j) acc[i][j] = (f32x4){0.f, 0.f, 0.f, 0.f};

    for (int chunk = 0; chunk < 8; ++chunk) {
        if (chunk >= 4) {
            const int kb = (chunk - 4) * 32;
            #pragma unroll
            for (int it = 0; it < 2; ++it) {
                int s = tid + it * 256;
                int r = s >> 2, p = s & 3;
                int gm = m0 + r;
                uint4 v = make_uint4(0u, 0u, 0u, 0u);
                if (gm < M) v = *(const uint4*)(hB + (size_t)gm * 128 + kb + p * 8);
                *(uint4*)&As[r * 40 + p * 8] = v;
            }
        }
        {
            const int kbB = chunk * 32;
            #pragma unroll
            for (int it = 0; it < 2; ++it) {
                int s = tid + it * 256;
                int r = s >> 2, p = s & 3;
                uint4 v = *(const uint4*)(B + (size_t)r * 256 + kbB + p * 8);
                *(uint4*)&Bs[r * 40 + p * 8] = v;
            }
        }
        __syncthreads();
        bf16x8 af[4], bfr[4];
        if (chunk < 4) {
            #pragma unroll
            for (int i = 0; i < 4; ++i)
                af[i] = *(const bf16x8*)&Ag[(wr * 64 + i * 16 + m16) * 136 + chunk * 32 + q * 8];
        } else {
            #pragma unroll
            for (int i = 0; i < 4; ++i)
                af[i] = *(const bf16x8*)&As[(wr * 64 + i * 16 + m16) * 40 + q * 8];
        }
        #pragma unroll
        for (int j = 0; j < 4; ++j)
            bfr[j] = *(const bf16x8*)&Bs[(wc * 64 + j * 16 + m16) * 40 + q * 8];
        #pragma unroll
        for (int i = 0; i < 4; ++i)
            #pragma unroll
            for (int j = 0; j < 4; ++j)
                acc[i][j] = __builtin_amdgcn_mfma_f32_16x16x32_bf16(af[i], bfr[j], acc[i][j], 0, 0, 0);
        __syncthreads();
    }

    float cs[4] = {0.f, 0.f, 0.f, 0.f};
    float cq[4] = {0.f, 0.f, 0.f, 0.f};
    #pragma unroll
    for (int i = 0; i < 4; ++i) {
        int mBase = m0 + wr * 64 + i * 16 + q * 4;
        #pragma unroll
        for (int j = 0; j < 4; ++j) {
            int cc = wc * 64 + j * 16 + m16;
            float bv = bias[cc];
            #pragma unroll
            for (int r = 0; r < 4; ++r) {
                int m = mBase + r;
                float v = (m < M) ? (acc[i][j][r] + bv) : 0.0f;
                if (m < M) outB[(size_t)m * 128 + cc] = f2b(v);
                cs[j] += v;
                cq[j] += v * v;
            }
        }
    }
    #pragma unroll
    for (int msk = 16; msk < 64; msk <<= 1) {
        #pragma unroll
        for (int j = 0; j < 4; ++j) {
            cs[j] += __shfl_xor(cs[j], msk, 64);
            cq[j] += __shfl_xor(cq[j], msk, 64);
        }
    }
    if (q == 0) {
        #pragma unroll
        for (int j = 0; j < 4; ++j) {
            int cc = wc * 64 + j * 16 + m16;
            redS[wr][cc] = cs[j];
            redQ[wr][cc] = cq[j];
        }
    }
    __syncthreads();
    if (tid < 128) {
        psPart[(size_t)blockIdx.x * 128 + tid] = redS[0][tid] + redS[1][tid];
        pqPart[(size_t)blockIdx.x * 128 + tid] = redQ[0][tid] + redQ[1][tid];
    }
}

// ---------------------------------------------------------------------------
// GraphNorm final coeffs: 1024 threads = 8 slices x 128 channels, LDS reduce
// ---------------------------------------------------------------------------
__global__ __launch_bounds__(1024) void k_gn_final(const float* __restrict__ ps,
        const float* __restrict__ pq, const float* __restrict__ gw,
        const float* __restrict__ gb, const float* __restrict__ ga,
        float* __restrict__ cA, float* __restrict__ cB, int nP) {
    __shared__ float shs[8][128], shq[8][128];
    int c = threadIdx.x & 127, sl = threadIdx.x >> 7;
    float s = 0.0f, q = 0.0f;
    for (int b = sl; b < nP; b += 8) {
        s += ps[b * 128 + c];
        q += pq[b * 128 + c];
    }
    shs[sl][c] = s;
    shq[sl][c] = q;
    __syncthreads();
    if (threadIdx.x < 128) {
        float S = 0.0f, Q = 0.0f;
        #pragma unroll
        for (int i = 0; i < 8; ++i) { S += shs[i][c]; Q += shq[i][c]; }
        float mean = S / (float)NN;
        float msq  = Q / (float)NN;
        float a = ga[c];
        float var = msq - mean * mean * a * (2.0f - a);
        float rstd = rsqrtf(var + 1e-5f);
        float A = gw[c] * rstd;
        cA[c] = A;
        cB[c] = gb[c] - a * mean * A;
    }
}

// ---------------------------------------------------------------------------
// GraphNorm apply: affine+GELU, yB (bf16, row-major) -> hB (bf16, row-major)
// ---------------------------------------------------------------------------
__global__ __launch_bounds__(256) void k_gn_apply(const unsigned short* __restrict__ yB,
        const float* __restrict__ cA, const float* __restrict__ cB,
        unsigned short* __restrict__ hB) {
    int i = blockIdx.x * 256 + threadIdx.x;  // uint4 index (8 bf16)
    if (i >= NN * 16) return;
    int g = i & 15;                          // channel group (8 ch)
    uint4 v = ((const uint4*)yB)[i];
    float4 A0 = ((const float4*)cA)[g * 2];
    float4 A1 = ((const float4*)cA)[g * 2 + 1];
    float4 B0 = ((const float4*)cB)[g * 2];
    float4 B1 = ((const float4*)cB)[g * 2 + 1];
    unsigned int o0 = pk2(gelu_exact(lof(v.x) * A0.x + B0.x),
                          gelu_exact(hif(v.x) * A0.y + B0.y));
    unsigned int o1 = pk2(gelu_exact(lof(v.y) * A0.z + B0.z),
                          gelu_exact(hif(v.y) * A0.w + B0.w));
    unsigned int o2 = pk2(gelu_exact(lof(v.z) * A1.x + B1.x),
                          gelu_exact(hif(v.z) * A1.y + B1.y));
    unsigned int o3 = pk2(gelu_exact(lof(v.w) * A1.z + B1.z),
                          gelu_exact(hif(v.w) * A1.w + B1.w));
    ((uint4*)hB)[i] = make_uint4(o0, o1, o2, o3);
}

// ---------------------------------------------------------------------------
// Fused head with layer-2 GraphNorm apply folded into staging:
// h = gelu(y*cA+cB) computed on load; 64-col phase 1; LDS pool alias (23 KB)
// ---------------------------------------------------------------------------
__global__ __launch_bounds__(256) void k_headf(const unsigned short* __restrict__ yB,
        const float* __restrict__ cAp, const float* __restrict__ cBp,
        const unsigned short* __restrict__ W1b, const float* __restrict__ b1,
        const unsigned short* __restrict__ W2b, const float* __restrict__ b2,
        const float* __restrict__ W3, const float* __restrict__ b3,
        float* __restrict__ out) {
    __shared__ __align__(16) char pool[23040];
    unsigned short* As  = (unsigned short*)pool;             // 128 x 40
    unsigned short* Bs  = (unsigned short*)(pool + 10240);   // 64 x 40
    unsigned short* As2 = (unsigned short*)pool;             // 128 x 72
    unsigned short* Bs2 = (unsigned short*)(pool + 18432);   // 32 x 72
    const int tid = threadIdx.x;
    const int m0 = blockIdx.x * 128;
    const int w = tid >> 6, lane = tid & 63;
    const int m16 = lane & 15, q = lane >> 4;
    const float4* cA4 = (const float4*)cAp;
    const float4* cB4 = (const float4*)cBp;

    #pragma unroll
    for (int it = 0; it < 8; ++it) {
        int i = tid + it * 256;
        if (i < 2048) Bs2[(i >> 6) * 72 + (i & 63)] = W2b[i];
    }

    f32x4 acc1[2][4];
    #pragma unroll
    for (int i = 0; i < 2; ++i)
        #pragma unroll
        for (int j = 0; j < 4; ++j) acc1[i][j] = (f32x4){0.f, 0.f, 0.f, 0.f};

    for (int chunk = 0; chunk < 4; ++chunk) {
        const int kb = chunk * 32;
        #pragma unroll
        for (int it = 0; it < 2; ++it) {
            int s = tid + it * 256;
            int r = s >> 2, p = s & 3;
            int gm = m0 + r;
            uint4 v = make_uint4(0u, 0u, 0u, 0u);
            if (gm < NN) v = *(const uint4*)(yB + (size_t)gm * 128 + kb + p * 8);
            int cg = chunk * 8 + p * 2;
            float4 Ax = cA4[cg], Ay = cA4[cg + 1];
            float4 Bx = cB4[cg], By = cB4[cg + 1];
            uint4 o;
            o.x = pk2(gelu_exact(lof(v.x) * Ax.x + Bx.x),
                      gelu_exact(hif(v.x) * Ax.y + Bx.y));
            o.y = pk2(gelu_exact(lof(v.y) * Ax.z + Bx.z),
                      gelu_exact(hif(v.y) * Ax.w + Bx.w));
            o.z = pk2(gelu_exact(lof(v.z) * Ay.x + By.x),
                      gelu_exact(hif(v.z) * Ay.y + By.y));
            o.w = pk2(gelu_exact(lof(v.w) * Ay.z + By.z),
                      gelu_exact(hif(v.w) * Ay.w + By.w));
            *(uint4*)&As[r * 40 + p * 8] = o;
        }
        {
            int r = tid >> 2, p = tid & 3;
            uint4 v = *(const uint4*)(W1b + (size_t)r * 128 + kb + p * 8);
            *(uint4*)&Bs[r * 40 + p * 8] = v;
        }
        __syncthreads();
        bf16x8 af[2], bfr[4];
        #pragma unroll
        for (int i = 0; i < 2; ++i)
            af[i] = *(const bf16x8*)&As[(w * 32 + i * 16 + m16) * 40 + q * 8];
        #pragma unroll
        for (int j = 0; j < 4; ++j)
            bfr[j] = *(const bf16x8*)&Bs[(j * 16 + m16) * 40 + q * 8];
        #pragma unroll
        for (int i = 0; i < 2; ++i)
            #pragma unroll
            for (int j = 0; j < 4; ++j)
                acc1[i][j] = __builtin_amdgcn_mfma_f32_16x16x32_bf16(af[i], bfr[j], acc1[i][j], 0, 0, 0);
        __syncthreads();
    }

    {
        float b1v[4];
        #pragma unroll
        for (int j = 0; j < 4; ++j) b1v[j] = b1[j * 16 + m16];
        #pragma unroll
        for (int i = 0; i < 2; ++i) {
            int mloc = w * 32 + i * 16 + q * 4;
            #pragma unroll
            for (int j = 0; j < 4; ++j) {
                int c = j * 16 + m16;
                #pragma unroll
                for (int r = 0; r < 4; ++r)
                    As2[(mloc + r) * 72 + c] = f2b(gelu_exact(acc1[i][j][r] + b1v[j]));
            }
        }
    }
    __syncthreads();

    f32x4 acc2[2][2];
    #pragma unroll
    for (int i = 0; i < 2; ++i)
        #pragma unroll
        for (int j = 0; j < 2; ++j) acc2[i][j] = (f32x4){0.f, 0.f, 0.f, 0.f};
    #pragma unroll
    for (int kc = 0; kc < 2; ++kc) {
        bf16x8 a2[2], bf2[2];
        #pragma unroll
        for (int i = 0; i < 2; ++i)
            a2[i] = *(const bf16x8*)&As2[(w * 32 + i * 16 + m16) * 72 + kc * 32 + q * 8];
        #pragma unroll
        for (int j = 0; j < 2; ++j)
            bf2[j] = *(const bf16x8*)&Bs2[(j * 16 + m16) * 72 + kc * 32 + q * 8];
        #pragma unroll
        for (int i = 0; i < 2; ++i)
            #pragma unroll
            for (int j = 0; j < 2; ++j)
                acc2[i][j] = __builtin_amdgcn_mfma_f32_16x16x32_bf16(a2[i], bf2[j], acc2[i][j], 0, 0, 0);
    }

    float w3a = W3[m16], w3b = W3[16 + m16];
    float b2a = b2[m16], b2b = b2[16 + m16];
    float p[8];
    #pragma unroll
    for (int i = 0; i < 2; ++i)
        #pragma unroll
        for (int r = 0; r < 4; ++r) {
            float za = gelu_exact(acc2[i][0][r] + b2a);
            float zb = gelu_exact(acc2[i][1][r] + b2b);
            p[i * 4 + r] = za * w3a + zb * w3b;
        }
    #pragma unroll
    for (int msk = 1; msk < 16; msk <<= 1)
        #pragma unroll
        for (int k = 0; k < 8; ++k) p[k] += __shfl_xor(p[k], msk, 64);
    if (m16 == 0) {
        float b3v = b3[0];
        #pragma unroll
        for (int i = 0; i < 2; ++i)
            #pragma unroll
            for (int r = 0; r < 4; ++r) {
                int m = m0 + w * 32 + i * 16 + q * 4 + r;
                if (m < NN) out[m] = 1.0f / (1.0f + expf(-(p[i * 4 + r] + b3v)));
            }
    }
}

// ---------------------------------------------------------------------------
// Launch (14 dispatches)
// ---------------------------------------------------------------------------
extern "C" void kernel_launch(void* const* d_in, const int* in_sizes, int n_in,
                              void* d_out, int out_size, void* d_ws, size_t ws_size,
                              hipStream_t stream) {
    const float* x   = (const float*)d_in[0];
    const int*   ei  = (const int*)d_in[1];
    const float* Wl0 = (const float*)d_in[2];
    const float* bl0 = (const float*)d_in[3];
    const float* Wr0 = (const float*)d_in[4];
    const float* gw0 = (const float*)d_in[5];
    const float* gb0 = (const float*)d_in[6];
    const float* ga0 = (const float*)d_in[7];
    const float* Wl1 = (const float*)d_in[8];
    const float* bl1 = (const float*)d_in[9];
    const float* Wr1 = (const float*)d_in[10];
    const float* gw1 = (const float*)d_in[11];
    const float* gb1 = (const float*)d_in[12];
    const float* ga1 = (const float*)d_in[13];
    const float* Wl2 = (const float*)d_in[14];
    const float* bl2 = (const float*)d_in[15];
    const float* Wr2 = (const float*)d_in[16];
    const float* gw2 = (const float*)d_in[17];
    const float* gb2 = (const float*)d_in[18];
    const float* ga2 = (const float*)d_in[19];
    const float* hW1 = (const float*)d_in[20];
    const float* hb1 = (const float*)d_in[21];
    const float* hW2 = (const float*)d_in[22];
    const float* hb2 = (const float*)d_in[23];
    const float* hW3 = (const float*)d_in[24];
    const float* hb3 = (const float*)d_in[25];
    float* out = (float*)d_out;

    size_t off = 0;
    auto carve = [&](size_t bytes) -> void* {
        void* p = (void*)((char*)d_ws + off);
        off += (bytes + 255) & ~(size_t)255;
        return p;
    };
    int*   bcnt      = (int*)carve((size_t)NBUK * 4);
    int*   bbase     = (int*)carve((size_t)(NBUK + 1) * 4);
    int*   cursor    = (int*)carve((size_t)NBUK * 4);
    unsigned int* pairs = (unsigned int*)carve((size_t)EE * 4);
    int*   deg       = (int*)carve((size_t)NN * 4);
    int*   row_start = (int*)carve((size_t)NN * 4);
    float* invdeg    = (float*)carve((size_t)NN * 4);
    int*   colarr    = (int*)carve((size_t)EE * 4);
    unsigned short* xb    = (unsigned short*)carve((size_t)NN * 32 * 2);
    unsigned short* Wt0   = (unsigned short*)carve(128 * 64 * 2);
    unsigned short* Wt2a  = (unsigned short*)carve(128 * 256 * 2);
    unsigned short* Wt2b  = (unsigned short*)carve(128 * 256 * 2);
    unsigned short* W1b   = (unsigned short*)carve(64 * 128 * 2);
    unsigned short* W2b   = (unsigned short*)carve(32 * 64 * 2);
    float* biasH1    = (float*)carve(64 * 4);
    float* biasH2    = (float*)carve(32 * 4);
    float* ps        = (float*)carve((size_t)MMB * 128 * 4);
    float* pq        = (float*)carve((size_t)MMB * 128 * 4);
    float* cAall     = (float*)carve(3 * 128 * 4);
    float* cBall     = (float*)carve(3 * 128 * 4);
    unsigned short* hB   = (unsigned short*)carve((size_t)NN * HH * 2);
    unsigned short* yB   = (unsigned short*)carve((size_t)NN * HH * 2);
    if (off > ws_size) return;

    const int* src = ei;
    const int* dst = ei + EE;

    // Packing (also zero-inits bcnt) + CSR build
    k_pack_all<<<(PACK_TOTAL + 255) / 256, 256, 0, stream>>>(
        x, Wl0, Wr0, Wl1, Wr1, Wl2, Wr2, hW1, hW2, hb1, hb2,
        xb, Wt0, Wt2a, Wt2b, W1b, W2b, biasH1, biasH2, bcnt);
    kb_cnt<<<FILLB, 256, 0, stream>>>(dst, bcnt);
    kb_scan<<<1, 512, 0, stream>>>(bcnt, bbase, cursor);
    kb_fill<<<FILLB, 256, 0, stream>>>(src, dst, cursor, pairs);
    kb_csr<<<NBUK, 256, 0, stream>>>(pairs, bbase, row_start, deg, invdeg, colarr);

    // Layer 0: fused gather + K=64 MFMA GEMM
    k_mm0<<<MMB, 256, 0, stream>>>((const uint2*)xb, row_start, deg, invdeg,
                                   colarr, Wt0, bl0, yB, ps, pq, NN);
    k_gn_final<<<1, 1024, 0, stream>>>(ps, pq, gw0, gb0, ga0, cAall + 0, cBall + 0, MMB);
    k_gn_apply<<<(NN * 16 + 255) / 256, 256, 0, stream>>>(yB, cAall + 0, cBall + 0, hB);

    // Layer 1: fused gather + K=256 MFMA GEMM
    k_mmagg<<<MMB, 256, 0, stream>>>(hB, row_start, deg, invdeg, colarr,
                                     Wt2a, bl1, yB, ps, pq, NN);
    k_gn_final<<<1, 1024, 0, stream>>>(ps, pq, gw1, gb1, ga1, cAall + 128, cBall + 128, MMB);
    k_gn_apply<<<(NN * 16 + 255) / 256, 256, 0, stream>>>(yB, cAall + 128, cBall + 128, hB);

    // Layer 2: fused gather + GEMM (GraphNorm apply deferred into head)
    k_mmagg<<<MMB, 256, 0, stream>>>(hB, row_start, deg, invdeg, colarr,
                                     Wt2b, bl2, yB, ps, pq, NN);
    k_gn_final<<<1, 1024, 0, stream>>>(ps, pq, gw2, gb2, ga2, cAall + 256, cBall + 256, MMB);

    // Fused head (applies layer-2 GraphNorm+GELU during staging)
    k_headf<<<MMB, 256, 0, stream>>>(yB, cAall + 256, cBall + 256,
                                     W1b, biasH1, W2b, biasH2, hW3, hb3, out);
}

// Round 12
// 660.386 us; speedup vs baseline: 1.4982x; 1.4982x over previous
//
#include <hip/hip_runtime.h>
#include <hip/hip_bf16.h>
#include <math.h>

// Problem constants
#define NN 100000
#define EE 1600000
#define FIN 20
#define HH 128
#define NBUK 391         // ceil(NN/256) buckets of 256 nodes
#define FILLB 196        // ceil(EE/8192) fill blocks
#define MMB 782          // ceil(NN/128) GEMM row-tiles
#define CAP 6144         // per-bucket capacity (mean 4096, +32 sigma)

typedef __attribute__((ext_vector_type(8))) short bf16x8;
typedef __attribute__((ext_vector_type(4))) float f32x4;

__device__ __forceinline__ unsigned short f2b(float x) {
    unsigned int b = __float_as_uint(x);
    unsigned int r = b + 0x7fffu + ((b >> 16) & 1u);
    return (unsigned short)(r >> 16);
}
__device__ __forceinline__ float lof(unsigned int u) { return __uint_as_float(u << 16); }
__device__ __forceinline__ float hif(unsigned int u) { return __uint_as_float(u & 0xffff0000u); }
__device__ __forceinline__ unsigned int pk2(float a, float b) {
    return (unsigned int)f2b(a) | ((unsigned int)f2b(b) << 16);
}

__device__ __forceinline__ float gelu_exact(float z) {
    return 0.5f * z * (1.0f + erff(z * 0.70710678118654752f));
}

// ---------------------------------------------------------------------------
// CSR build: direct-fill binning (fixed per-bucket capacity, no prefix scan)
// ---------------------------------------------------------------------------
__global__ __launch_bounds__(256) void kb_fill(const int* __restrict__ src,
        const int* __restrict__ dst, int* __restrict__ cursor,
        unsigned int* __restrict__ pairs) {
    __shared__ int cnt[NBUK], base[NBUK], boff[NBUK];
    int t = threadIdx.x;
    for (int i = t; i < NBUK; i += 256) { cnt[i] = 0; boff[i] = 0; }
    __syncthreads();
    int e0 = blockIdx.x * 8192;
    #pragma unroll 4
    for (int i = 0; i < 32; ++i) {
        int e = e0 + i * 256 + t;
        if (e < EE) atomicAdd(&cnt[dst[e] >> 8], 1);
    }
    __syncthreads();
    for (int i = t; i < NBUK; i += 256)
        if (cnt[i]) base[i] = atomicAdd(&cursor[i], cnt[i]);
    __syncthreads();
    #pragma unroll 4
    for (int i = 0; i < 32; ++i) {
        int e = e0 + i * 256 + t;
        if (e < EE) {
            int d = dst[e];
            int b = d >> 8;
            int pos = base[b] + atomicAdd(&boff[b], 1);
            pairs[(size_t)b * CAP + pos] = (unsigned int)src[e]
                                         | ((unsigned int)(d & 255) << 17);
        }
    }
}

__global__ __launch_bounds__(256) void kb_csr(const unsigned int* __restrict__ pairs,
        const int* __restrict__ cursor, int* __restrict__ row_start,
        int* __restrict__ deg, float* __restrict__ invdeg, int* __restrict__ col) {
    __shared__ int ldeg[256];
    __shared__ int lcnt[256];
    __shared__ int colL[CAP];
    int b = blockIdx.x, t = threadIdx.x;
    int e0 = b * CAP;
    int cb = cursor[b];          // edges in this bucket
    ldeg[t] = 0;
    lcnt[t] = 0;
    __syncthreads();
    for (int e = t; e < cb; e += 256) atomicAdd(&ldeg[pairs[e0 + e] >> 17], 1);
    __syncthreads();
    int d = ldeg[t];
    for (int off = 1; off < 256; off <<= 1) {
        int add = (t >= off) ? ldeg[t - off] : 0;
        __syncthreads();
        ldeg[t] += add;
        __syncthreads();
    }
    int n = b * 256 + t;
    if (n < NN) {
        row_start[n] = e0 + ldeg[t] - d;
        deg[n] = d;
        invdeg[n] = 1.0f / fmaxf((float)d, 1.0f);
    }
    __syncthreads();
    for (int e = t; e < cb; e += 256) {
        unsigned int p = pairs[e0 + e];
        int dL = p >> 17;
        int pos = (dL ? ldeg[dL - 1] : 0) + atomicAdd(&lcnt[dL], 1);
        colL[pos] = (int)(p & 0x1FFFFu);
    }
    __syncthreads();
    for (int e = t; e < cb; e += 256) col[e0 + e] = colL[e];   // coalesced
}

// ---------------------------------------------------------------------------
// Mega-pack: xb, Wt0, Wt2a, Wt2b, W1b, W2b, biases, cursor zero-init
// ---------------------------------------------------------------------------
#define XB_N  (NN * 32)
#define PACK_TOTAL (XB_N + 8192 + 32768 + 32768 + 8192 + 2048 + 64 + 32 + NBUK)
__global__ __launch_bounds__(256) void k_pack_all(const float* __restrict__ x,
        const float* __restrict__ Wl0, const float* __restrict__ Wr0,
        const float* __restrict__ Wl1, const float* __restrict__ Wr1,
        const float* __restrict__ Wl2, const float* __restrict__ Wr2,
        const float* __restrict__ hW1, const float* __restrict__ hW2,
        const float* __restrict__ hb1, const float* __restrict__ hb2,
        unsigned short* __restrict__ xb,
        unsigned short* __restrict__ Wt0, unsigned short* __restrict__ Wt2a,
        unsigned short* __restrict__ Wt2b, unsigned short* __restrict__ W1b,
        unsigned short* __restrict__ W2b, float* __restrict__ bH1,
        float* __restrict__ bH2, int* __restrict__ cursor) {
    int id = blockIdx.x * 256 + threadIdx.x;
    if (id < XB_N) {
        int n = id >> 5, k = id & 31;
        xb[id] = f2b((k < FIN) ? x[n * FIN + k] : 0.0f);
        return;
    }
    id -= XB_N;
    if (id < 8192) {  // Wt0: 128 x 64  [Wl0(20)|0|Wr0(20)|0]
        int c = id >> 6, k = id & 63;
        float v = 0.0f;
        if (k < FIN) v = Wl0[c * FIN + k];
        else if (k >= 32 && k < 32 + FIN) v = Wr0[c * FIN + (k - 32)];
        Wt0[id] = f2b(v);
        return;
    }
    id -= 8192;
    if (id < 32768) {  // layer-1 weights 128 x 256
        int c = id >> 8, k = id & 255;
        Wt2a[id] = f2b((k < HH) ? Wl1[c * HH + k] : Wr1[c * HH + (k - HH)]);
        return;
    }
    id -= 32768;
    if (id < 32768) {  // layer-2 weights
        int c = id >> 8, k = id & 255;
        Wt2b[id] = f2b((k < HH) ? Wl2[c * HH + k] : Wr2[c * HH + (k - HH)]);
        return;
    }
    id -= 32768;
    if (id < 8192) { W1b[id] = f2b(hW1[id]); return; }   // 64 x 128
    id -= 8192;
    if (id < 2048) { W2b[id] = f2b(hW2[id]); return; }   // 32 x 64
    id -= 2048;
    if (id < 64) { bH1[id] = hb1[id]; return; }
    id -= 64;
    if (id < 32) { bH2[id] = hb2[id]; return; }
    id -= 32;
    if (id < NBUK) { cursor[id] = 0; return; }
}

// ---------------------------------------------------------------------------
// Layer 0 fused: per-block gather (xb 64 B rows) + x-copy into LDS A-tile,
// then K=64 MFMA GEMM with fused GraphNorm partial stats.
// ---------------------------------------------------------------------------
__global__ __launch_bounds__(256) void k_mm0(const uint2* __restrict__ xb2,
        const int* __restrict__ rs, const int* __restrict__ deg,
        const float* __restrict__ inv, const int* __restrict__ col,
        const unsigned short* __restrict__ B, const float* __restrict__ bias,
        unsigned short* __restrict__ outB, float* __restrict__ psPart,
        float* __restrict__ pqPart, int M) {
    __shared__ __align__(16) unsigned short Ag[128 * 72];  // K=64, stride 72
    __shared__ __align__(16) unsigned short Bs[128 * 40];
    __shared__ float redS[2][128], redQ[2][128];
    const int tid = threadIdx.x;
    const int m0 = blockIdx.x * 128;
    const int w = tid >> 6, lane = tid & 63;
    const int wr = w >> 1, wc = w & 1;
    const int m16 = lane & 15, q = lane >> 4;
    const int er = lane >> 3, c8 = lane & 7;

    for (int nn = w; nn < 128; nn += 4) {
        int n = m0 + nn;
        float a0 = 0.f, a1 = 0.f, a2 = 0.f, a3 = 0.f;
        if (n < M) {
            int s = rs[n], d = deg[n];
            for (int j0 = 0; j0 < d; j0 += 8) {
                int j = j0 + er;
                if (j < d) {
                    int c = col[s + j];
                    uint2 v = xb2[(size_t)c * 8 + c8];
                    a0 += lof(v.x); a1 += hif(v.x);
                    a2 += lof(v.y); a3 += hif(v.y);
                }
            }
            #pragma unroll
            for (int m = 8; m < 64; m <<= 1) {
                a0 += __shfl_xor(a0, m, 64);
                a1 += __shfl_xor(a1, m, 64);
                a2 += __shfl_xor(a2, m, 64);
                a3 += __shfl_xor(a3, m, 64);
            }
        }
        if (er == 0) {
            float iv = (n < M) ? inv[n] : 0.0f;
            uint2 o = make_uint2(0u, 0u);
            if (c8 < 5) { o.x = pk2(a0 * iv, a1 * iv); o.y = pk2(a2 * iv, a3 * iv); }
            *(uint2*)&Ag[nn * 72 + c8 * 4] = o;           // cols 0..31
        } else if (er == 1) {
            uint2 v = make_uint2(0u, 0u);
            if (n < M) v = xb2[(size_t)n * 8 + c8];
            *(uint2*)&Ag[nn * 72 + 32 + c8 * 4] = v;      // cols 32..63
        }
    }

    f32x4 acc[4][4];
    #pragma unroll
    for (int i = 0; i < 4; ++i)
        #pragma unroll
        for (int j = 0; j < 4; ++j) acc[i][j] = (f32x4){0.f, 0.f, 0.f, 0.f};

    for (int chunk = 0; chunk < 2; ++chunk) {
        const int kb = chunk * 32;
        #pragma unroll
        for (int it = 0; it < 2; ++it) {
            int s = tid + it * 256;
            int r = s >> 2, p = s & 3;
            uint4 v = *(const uint4*)(B + (size_t)r * 64 + kb + p * 8);
            *(uint4*)&Bs[r * 40 + p * 8] = v;
        }
        __syncthreads();
        bf16x8 af[4], bfr[4];
        #pragma unroll
        for (int i = 0; i < 4; ++i)
            af[i] = *(const bf16x8*)&Ag[(wr * 64 + i * 16 + m16) * 72 + kb + q * 8];
        #pragma unroll
        for (int j = 0; j < 4; ++j)
            bfr[j] = *(const bf16x8*)&Bs[(wc * 64 + j * 16 + m16) * 40 + q * 8];
        #pragma unroll
        for (int i = 0; i < 4; ++i)
            #pragma unroll
            for (int j = 0; j < 4; ++j)
                acc[i][j] = __builtin_amdgcn_mfma_f32_16x16x32_bf16(af[i], bfr[j], acc[i][j], 0, 0, 0);
        __syncthreads();
    }

    float cs[4] = {0.f, 0.f, 0.f, 0.f};
    float cq[4] = {0.f, 0.f, 0.f, 0.f};
    #pragma unroll
    for (int i = 0; i < 4; ++i) {
        int mBase = m0 + wr * 64 + i * 16 + q * 4;
        #pragma unroll
        for (int j = 0; j < 4; ++j) {
            int cc = wc * 64 + j * 16 + m16;
            float bv = bias[cc];
            #pragma unroll
            for (int r = 0; r < 4; ++r) {
                int m = mBase + r;
                float v = (m < M) ? (acc[i][j][r] + bv) : 0.0f;
                if (m < M) outB[(size_t)m * 128 + cc] = f2b(v);
                cs[j] += v;
                cq[j] += v * v;
            }
        }
    }
    #pragma unroll
    for (int msk = 16; msk < 64; msk <<= 1) {
        #pragma unroll
        for (int j = 0; j < 4; ++j) {
            cs[j] += __shfl_xor(cs[j], msk, 64);
            cq[j] += __shfl_xor(cq[j], msk, 64);
        }
    }
    if (q == 0) {
        #pragma unroll
        for (int j = 0; j < 4; ++j) {
            int cc = wc * 64 + j * 16 + m16;
            redS[wr][cc] = cs[j];
            redQ[wr][cc] = cq[j];
        }
    }
    __syncthreads();
    if (tid < 128) {
        psPart[(size_t)blockIdx.x * 128 + tid] = redS[0][tid] + redS[1][tid];
        pqPart[(size_t)blockIdx.x * 128 + tid] = redQ[0][tid] + redQ[1][tid];
    }
}

// ---------------------------------------------------------------------------
// Wide bf16 aggregation (round-3 form): 1 wave per node, lane = 2 channels,
// full 256 B coalesced row reads — at the LLC-bandwidth roofline (~60 us).
// ---------------------------------------------------------------------------
__global__ __launch_bounds__(64) void k_aggb(const unsigned short* __restrict__ hB,
        const int* __restrict__ rs, const int* __restrict__ deg,
        const float* __restrict__ inv, const int* __restrict__ col,
        unsigned short* __restrict__ aggB) {
    int n = blockIdx.x;
    int t = threadIdx.x;
    int s = rs[n], d = deg[n];
    const unsigned int* h32 = (const unsigned int*)hB;
    float a0 = 0.0f, a1 = 0.0f;
    int j = 0;
    for (; j + 3 < d; j += 4) {
        int c0 = col[s + j], c1 = col[s + j + 1];
        int c2 = col[s + j + 2], c3 = col[s + j + 3];
        unsigned int u0 = h32[(size_t)c0 * 64 + t];
        unsigned int u1 = h32[(size_t)c1 * 64 + t];
        unsigned int u2 = h32[(size_t)c2 * 64 + t];
        unsigned int u3 = h32[(size_t)c3 * 64 + t];
        a0 += lof(u0) + lof(u1) + lof(u2) + lof(u3);
        a1 += hif(u0) + hif(u1) + hif(u2) + hif(u3);
    }
    for (; j < d; ++j) {
        unsigned int u = h32[(size_t)col[s + j] * 64 + t];
        a0 += lof(u);
        a1 += hif(u);
    }
    float iv = inv[n];
    ((unsigned int*)aggB)[(size_t)n * 64 + t] = pk2(a0 * iv, a1 * iv);
}

// ---------------------------------------------------------------------------
// bf16 MFMA GEMM with per-block GraphNorm partial stats.
// ---------------------------------------------------------------------------
__global__ __launch_bounds__(256) void k_mm(const unsigned short* __restrict__ A0,
        const unsigned short* __restrict__ A1, int c0, int kChunks, int lda,
        const unsigned short* __restrict__ B, int ldb,
        const float* __restrict__ bias, unsigned short* __restrict__ outB,
        float* __restrict__ psPart, float* __restrict__ pqPart, int M) {
    __shared__ __align__(16) unsigned short As[128 * 40];
    __shared__ __align__(16) unsigned short Bs[128 * 40];
    __shared__ float redS[2][128], redQ[2][128];
    const int tid = threadIdx.x;
    const int m0 = blockIdx.x * 128;
    const int w = tid >> 6, lane = tid & 63;
    const int wr = w >> 1, wc = w & 1;
    const int m16 = lane & 15, q = lane >> 4;

    f32x4 acc[4][4];
    #pragma unroll
    for (int i = 0; i < 4; ++i)
        #pragma unroll
        for (int j = 0; j < 4; ++j) acc[i][j] = (f32x4){0.f, 0.f, 0.f, 0.f};

    for (int chunk = 0; chunk < kChunks; ++chunk) {
        const unsigned short* A = (chunk < c0) ? A0 : A1;
        const int kb = (chunk - ((chunk < c0) ? 0 : c0)) * 32;
        #pragma unroll
        for (int it = 0; it < 2; ++it) {
            int s = tid + it * 256;
            int r = s >> 2, p = s & 3;
            int gm = m0 + r;
            uint4 v = make_uint4(0u, 0u, 0u, 0u);
            if (gm < M) v = *(const uint4*)(A + (size_t)gm * lda + kb + p * 8);
            *(uint4*)&As[r * 40 + p * 8] = v;
        }
        {
            const int kbB = chunk * 32;
            #pragma unroll
            for (int it = 0; it < 2; ++it) {
                int s = tid + it * 256;
                int r = s >> 2, p = s & 3;
                uint4 v = *(const uint4*)(B + (size_t)r * ldb + kbB + p * 8);
                *(uint4*)&Bs[r * 40 + p * 8] = v;
            }
        }
        __syncthreads();
        bf16x8 af[4], bfr[4];
        #pragma unroll
        for (int i = 0; i < 4; ++i)
            af[i] = *(const bf16x8*)&As[(wr * 64 + i * 16 + m16) * 40 + q * 8];
        #pragma unroll
        for (int j = 0; j < 4; ++j)
            bfr[j] = *(const bf16x8*)&Bs[(wc * 64 + j * 16 + m16) * 40 + q * 8];
        #pragma unroll
        for (int i = 0; i < 4; ++i)
            #pragma unroll
            for (int j = 0; j < 4; ++j)
                acc[i][j] = __builtin_amdgcn_mfma_f32_16x16x32_bf16(af[i], bfr[j], acc[i][j], 0, 0, 0);
        __syncthreads();
    }

    float cs[4] = {0.f, 0.f, 0.f, 0.f};
    float cq[4] = {0.f, 0.f, 0.f, 0.f};
    #pragma unroll
    for (int i = 0; i < 4; ++i) {
        int mBase = m0 + wr * 64 + i * 16 + q * 4;
        #pragma unroll
        for (int j = 0; j < 4; ++j) {
            int cc = wc * 64 + j * 16 + m16;
            float bv = bias[cc];
            #pragma unroll
            for (int r = 0; r < 4; ++r) {
                int m = mBase + r;
                float v = (m < M) ? (acc[i][j][r] + bv) : 0.0f;
                if (m < M) outB[(size_t)m * 128 + cc] = f2b(v);
                cs[j] += v;
                cq[j] += v * v;
            }
        }
    }
    #pragma unroll
    for (int msk = 16; msk < 64; msk <<= 1) {
        #pragma unroll
        for (int j = 0; j < 4; ++j) {
            cs[j] += __shfl_xor(cs[j], msk, 64);
            cq[j] += __shfl_xor(cq[j], msk, 64);
        }
    }
    if (q == 0) {
        #pragma unroll
        for (int j = 0; j < 4; ++j) {
            int cc = wc * 64 + j * 16 + m16;
            redS[wr][cc] = cs[j];
            redQ[wr][cc] = cq[j];
        }
    }
    __syncthreads();
    if (tid < 128) {
        psPart[(size_t)blockIdx.x * 128 + tid] = redS[0][tid] + redS[1][tid];
        pqPart[(size_t)blockIdx.x * 128 + tid] = redQ[0][tid] + redQ[1][tid];
    }
}

// ---------------------------------------------------------------------------
// GraphNorm final coeffs: 1024 threads = 8 slices x 128 channels, LDS reduce
// ---------------------------------------------------------------------------
__global__ __launch_bounds__(1024) void k_gn_final(const float* __restrict__ ps,
        const float* __restrict__ pq, const float* __restrict__ gw,
        const float* __restrict__ gb, const float* __restrict__ ga,
        float* __restrict__ cA, float* __restrict__ cB, int nP) {
    __shared__ float shs[8][128], shq[8][128];
    int c = threadIdx.x & 127, sl = threadIdx.x >> 7;
    float s = 0.0f, q = 0.0f;
    for (int b = sl; b < nP; b += 8) {
        s += ps[b * 128 + c];
        q += pq[b * 128 + c];
    }
    shs[sl][c] = s;
    shq[sl][c] = q;
    __syncthreads();
    if (threadIdx.x < 128) {
        float S = 0.0f, Q = 0.0f;
        #pragma unroll
        for (int i = 0; i < 8; ++i) { S += shs[i][c]; Q += shq[i][c]; }
        float mean = S / (float)NN;
        float msq  = Q / (float)NN;
        float a = ga[c];
        float var = msq - mean * mean * a * (2.0f - a);
        float rstd = rsqrtf(var + 1e-5f);
        float A = gw[c] * rstd;
        cA[c] = A;
        cB[c] = gb[c] - a * mean * A;
    }
}

// ---------------------------------------------------------------------------
// GraphNorm apply: affine+GELU, yB (bf16, row-major) -> hB (bf16, row-major)
// ---------------------------------------------------------------------------
__global__ __launch_bounds__(256) void k_gn_apply(const unsigned short* __restrict__ yB,
        const float* __restrict__ cA, const float* __restrict__ cB,
        unsigned short* __restrict__ hB) {
    int i = blockIdx.x * 256 + threadIdx.x;  // uint4 index (8 bf16)
    if (i >= NN * 16) return;
    int g = i & 15;                          // channel group (8 ch)
    uint4 v = ((const uint4*)yB)[i];
    float4 A0 = ((const float4*)cA)[g * 2];
    float4 A1 = ((const float4*)cA)[g * 2 + 1];
    float4 B0 = ((const float4*)cB)[g * 2];
    float4 B1 = ((const float4*)cB)[g * 2 + 1];
    unsigned int o0 = pk2(gelu_exact(lof(v.x) * A0.x + B0.x),
                          gelu_exact(hif(v.x) * A0.y + B0.y));
    unsigned int o1 = pk2(gelu_exact(lof(v.y) * A0.z + B0.z),
                          gelu_exact(hif(v.y) * A0.w + B0.w));
    unsigned int o2 = pk2(gelu_exact(lof(v.z) * A1.x + B1.x),
                          gelu_exact(hif(v.z) * A1.y + B1.y));
    unsigned int o3 = pk2(gelu_exact(lof(v.w) * A1.z + B1.z),
                          gelu_exact(hif(v.w) * A1.w + B1.w));
    ((uint4*)hB)[i] = make_uint4(o0, o1, o2, o3);
}

// ---------------------------------------------------------------------------
// Fused head with layer-2 GraphNorm apply folded into staging.
// ---------------------------------------------------------------------------
__global__ __launch_bounds__(256) void k_headf(const unsigned short* __restrict__ yB,
        const float* __restrict__ cAp, const float* __restrict__ cBp,
        const unsigned short* __restrict__ W1b, const float* __restrict__ b1,
        const unsigned short* __restrict__ W2b, const float* __restrict__ b2,
        const float* __restrict__ W3, const float* __restrict__ b3,
        float* __restrict__ out) {
    __shared__ __align__(16) char pool[23040];
    unsigned short* As  = (unsigned short*)pool;             // 128 x 40
    unsigned short* Bs  = (unsigned short*)(pool + 10240);   // 64 x 40
    unsigned short* As2 = (unsigned short*)pool;             // 128 x 72
    unsigned short* Bs2 = (unsigned short*)(pool + 18432);   // 32 x 72
    const int tid = threadIdx.x;
    const int m0 = blockIdx.x * 128;
    const int w = tid >> 6, lane = tid & 63;
    const int m16 = lane & 15, q = lane >> 4;
    const float4* cA4 = (const float4*)cAp;
    const float4* cB4 = (const float4*)cBp;

    #pragma unroll
    for (int it = 0; it < 8; ++it) {
        int i = tid + it * 256;
        if (i < 2048) Bs2[(i >> 6) * 72 + (i & 63)] = W2b[i];
    }

    f32x4 acc1[2][4];
    #pragma unroll
    for (int i = 0; i < 2; ++i)
        #pragma unroll
        for (int j = 0; j < 4; ++j) acc1[i][j] = (f32x4){0.f, 0.f, 0.f, 0.f};

    for (int chunk = 0; chunk < 4; ++chunk) {
        const int kb = chunk * 32;
        #pragma unroll
        for (int it = 0; it < 2; ++it) {
            int s = tid + it * 256;
            int r = s >> 2, p = s & 3;
            int gm = m0 + r;
            uint4 v = make_uint4(0u, 0u, 0u, 0u);
            if (gm < NN) v = *(const uint4*)(yB + (size_t)gm * 128 + kb + p * 8);
            int cg = chunk * 8 + p * 2;
            float4 Ax = cA4[cg], Ay = cA4[cg + 1];
            float4 Bx = cB4[cg], By = cB4[cg + 1];
            uint4 o;
            o.x = pk2(gelu_exact(lof(v.x) * Ax.x + Bx.x),
                      gelu_exact(hif(v.x) * Ax.y + Bx.y));
            o.y = pk2(gelu_exact(lof(v.y) * Ax.z + Bx.z),
                      gelu_exact(hif(v.y) * Ax.w + Bx.w));
            o.z = pk2(gelu_exact(lof(v.z) * Ay.x + By.x),
                      gelu_exact(hif(v.z) * Ay.y + By.y));
            o.w = pk2(gelu_exact(lof(v.w) * Ay.z + By.z),
                      gelu_exact(hif(v.w) * Ay.w + By.w));
            *(uint4*)&As[r * 40 + p * 8] = o;
        }
        {
            int r = tid >> 2, p = tid & 3;
            uint4 v = *(const uint4*)(W1b + (size_t)r * 128 + kb + p * 8);
            *(uint4*)&Bs[r * 40 + p * 8] = v;
        }
        __syncthreads();
        bf16x8 af[2], bfr[4];
        #pragma unroll
        for (int i = 0; i < 2; ++i)
            af[i] = *(const bf16x8*)&As[(w * 32 + i * 16 + m16) * 40 + q * 8];
        #pragma unroll
        for (int j = 0; j < 4; ++j)
            bfr[j] = *(const bf16x8*)&Bs[(j * 16 + m16) * 40 + q * 8];
        #pragma unroll
        for (int i = 0; i < 2; ++i)
            #pragma unroll
            for (int j = 0; j < 4; ++j)
                acc1[i][j] = __builtin_amdgcn_mfma_f32_16x16x32_bf16(af[i], bfr[j], acc1[i][j], 0, 0, 0);
        __syncthreads();
    }

    {
        float b1v[4];
        #pragma unroll
        for (int j = 0; j < 4; ++j) b1v[j] = b1[j * 16 + m16];
        #pragma unroll
        for (int i = 0; i < 2; ++i) {
            int mloc = w * 32 + i * 16 + q * 4;
            #pragma unroll
            for (int j = 0; j < 4; ++j) {
                int c = j * 16 + m16;
                #pragma unroll
                for (int r = 0; r < 4; ++r)
                    As2[(mloc + r) * 72 + c] = f2b(gelu_exact(acc1[i][j][r] + b1v[j]));
            }
        }
    }
    __syncthreads();

    f32x4 acc2[2][2];
    #pragma unroll
    for (int i = 0; i < 2; ++i)
        #pragma unroll
        for (int j = 0; j < 2; ++j) acc2[i][j] = (f32x4){0.f, 0.f, 0.f, 0.f};
    #pragma unroll
    for (int kc = 0; kc < 2; ++kc) {
        bf16x8 a2[2], bf2[2];
        #pragma unroll
        for (int i = 0; i < 2; ++i)
            a2[i] = *(const bf16x8*)&As2[(w * 32 + i * 16 + m16) * 72 + kc * 32 + q * 8];
        #pragma unroll
        for (int j = 0; j < 2; ++j)
            bf2[j] = *(const bf16x8*)&Bs2[(j * 16 + m16) * 72 + kc * 32 + q * 8];
        #pragma unroll
        for (int i = 0; i < 2; ++i)
            #pragma unroll
            for (int j = 0; j < 2; ++j)
                acc2[i][j] = __builtin_amdgcn_mfma_f32_16x16x32_bf16(a2[i], bf2[j], acc2[i][j], 0, 0, 0);
    }

    float w3a = W3[m16], w3b = W3[16 + m16];
    float b2a = b2[m16], b2b = b2[16 + m16];
    float p[8];
    #pragma unroll
    for (int i = 0; i < 2; ++i)
        #pragma unroll
        for (int r = 0; r < 4; ++r) {
            float za = gelu_exact(acc2[i][0][r] + b2a);
            float zb = gelu_exact(acc2[i][1][r] + b2b);
            p[i * 4 + r] = za * w3a + zb * w3b;
        }
    #pragma unroll
    for (int msk = 1; msk < 16; msk <<= 1)
        #pragma unroll
        for (int k = 0; k < 8; ++k) p[k] += __shfl_xor(p[k], msk, 64);
    if (m16 == 0) {
        float b3v = b3[0];
        #pragma unroll
        for (int i = 0; i < 2; ++i)
            #pragma unroll
            for (int r = 0; r < 4; ++r) {
                int m = m0 + w * 32 + i * 16 + q * 4 + r;
                if (m < NN) out[m] = 1.0f / (1.0f + expf(-(p[i * 4 + r] + b3v)));
            }
    }
}

// ---------------------------------------------------------------------------
// Launch (14 dispatches)
// ---------------------------------------------------------------------------
extern "C" void kernel_launch(void* const* d_in, const int* in_sizes, int n_in,
                              void* d_out, int out_size, void* d_ws, size_t ws_size,
                              hipStream_t stream) {
    const float* x   = (const float*)d_in[0];
    const int*   ei  = (const int*)d_in[1];
    const float* Wl0 = (const float*)d_in[2];
    const float* bl0 = (const float*)d_in[3];
    const float* Wr0 = (const float*)d_in[4];
    const float* gw0 = (const float*)d_in[5];
    const float* gb0 = (const float*)d_in[6];
    const float* ga0 = (const float*)d_in[7];
    const float* Wl1 = (const float*)d_in[8];
    const float* bl1 = (const float*)d_in[9];
    const float* Wr1 = (const float*)d_in[10];
    const float* gw1 = (const float*)d_in[11];
    const float* gb1 = (const float*)d_in[12];
    const float* ga1 = (const float*)d_in[13];
    const float* Wl2 = (const float*)d_in[14];
    const float* bl2 = (const float*)d_in[15];
    const float* Wr2 = (const float*)d_in[16];
    const float* gw2 = (const float*)d_in[17];
    const float* gb2 = (const float*)d_in[18];
    const float* ga2 = (const float*)d_in[19];
    const float* hW1 = (const float*)d_in[20];
    const float* hb1 = (const float*)d_in[21];
    const float* hW2 = (const float*)d_in[22];
    const float* hb2 = (const float*)d_in[23];
    const float* hW3 = (const float*)d_in[24];
    const float* hb3 = (const float*)d_in[25];
    float* out = (float*)d_out;

    size_t off = 0;
    auto carve = [&](size_t bytes) -> void* {
        void* p = (void*)((char*)d_ws + off);
        off += (bytes + 255) & ~(size_t)255;
        return p;
    };
    int*   cursor    = (int*)carve((size_t)NBUK * 4);
    unsigned int* pairs = (unsigned int*)carve((size_t)NBUK * CAP * 4);
    int*   deg       = (int*)carve((size_t)NN * 4);
    int*   row_start = (int*)carve((size_t)NN * 4);
    float* invdeg    = (float*)carve((size_t)NN * 4);
    int*   colarr    = (int*)carve((size_t)NBUK * CAP * 4);
    unsigned short* xb    = (unsigned short*)carve((size_t)NN * 32 * 2);
    unsigned short* Wt0   = (unsigned short*)carve(128 * 64 * 2);
    unsigned short* Wt2a  = (unsigned short*)carve(128 * 256 * 2);
    unsigned short* Wt2b  = (unsigned short*)carve(128 * 256 * 2);
    unsigned short* W1b   = (unsigned short*)carve(64 * 128 * 2);
    unsigned short* W2b   = (unsigned short*)carve(32 * 64 * 2);
    float* biasH1    = (float*)carve(64 * 4);
    float* biasH2    = (float*)carve(32 * 4);
    float* ps        = (float*)carve((size_t)MMB * 128 * 4);
    float* pq        = (float*)carve((size_t)MMB * 128 * 4);
    float* cAall     = (float*)carve(3 * 128 * 4);
    float* cBall     = (float*)carve(3 * 128 * 4);
    unsigned short* hB   = (unsigned short*)carve((size_t)NN * HH * 2);
    unsigned short* aggB = (unsigned short*)carve((size_t)NN * HH * 2);
    unsigned short* yB   = (unsigned short*)carve((size_t)NN * HH * 2);
    if (off > ws_size) return;

    const int* src = ei;
    const int* dst = ei + EE;

    // Packing (also zero-inits cursor) + direct-fill CSR build
    k_pack_all<<<(PACK_TOTAL + 255) / 256, 256, 0, stream>>>(
        x, Wl0, Wr0, Wl1, Wr1, Wl2, Wr2, hW1, hW2, hb1, hb2,
        xb, Wt0, Wt2a, Wt2b, W1b, W2b, biasH1, biasH2, cursor);
    kb_fill<<<FILLB, 256, 0, stream>>>(src, dst, cursor, pairs);
    kb_csr<<<NBUK, 256, 0, stream>>>(pairs, cursor, row_start, deg, invdeg, colarr);

    // Layer 0: fused gather + K=64 MFMA GEMM
    k_mm0<<<MMB, 256, 0, stream>>>((const uint2*)xb, row_start, deg, invdeg,
                                   colarr, Wt0, bl0, yB, ps, pq, NN);
    k_gn_final<<<1, 1024, 0, stream>>>(ps, pq, gw0, gb0, ga0, cAall + 0, cBall + 0, MMB);
    k_gn_apply<<<(NN * 16 + 255) / 256, 256, 0, stream>>>(yB, cAall + 0, cBall + 0, hB);

    // Layer 1
    k_aggb<<<NN, 64, 0, stream>>>(hB, row_start, deg, invdeg, colarr, aggB);
    k_mm<<<MMB, 256, 0, stream>>>(aggB, hB, 4, 8, 128, Wt2a, 256, bl1, yB, ps, pq, NN);
    k_gn_final<<<1, 1024, 0, stream>>>(ps, pq, gw1, gb1, ga1, cAall + 128, cBall + 128, MMB);
    k_gn_apply<<<(NN * 16 + 255) / 256, 256, 0, stream>>>(yB, cAall + 128, cBall + 128, hB);

    // Layer 2 (apply fused into head)
    k_aggb<<<NN, 64, 0, stream>>>(hB, row_start, deg, invdeg, colarr, aggB);
    k_mm<<<MMB, 256, 0, stream>>>(aggB, hB, 4, 8, 128, Wt2b, 256, bl2, yB, ps, pq, NN);
    k_gn_final<<<1, 1024, 0, stream>>>(ps, pq, gw2, gb2, ga2, cAall + 256, cBall + 256, MMB);

    // Fused head (applies layer-2 GraphNorm+GELU during staging)
    k_headf<<<MMB, 256, 0, stream>>>(yB, cAall + 256, cBall + 256,
                                     W1b, biasH1, W2b, biasH2, hW3, hb3, out);
}

// Round 13
// 546.371 us; speedup vs baseline: 1.8109x; 1.2087x over previous
//
#include <hip/hip_runtime.h>
#include <hip/hip_bf16.h>
#include <math.h>

// Problem constants
#define NN 100000
#define EE 1600000
#define FIN 20
#define HH 128
#define NBUK 391         // ceil(NN/256) buckets of 256 nodes
#define FILLB 196        // ceil(EE/8192) fill blocks
#define MMB 782          // ceil(NN/128) GEMM row-tiles
#define CAP 6144         // per-bucket capacity (mean 4096, +32 sigma)

typedef __attribute__((ext_vector_type(8))) short bf16x8;
typedef __attribute__((ext_vector_type(4))) float f32x4;

__device__ __forceinline__ unsigned short f2b(float x) {
    unsigned int b = __float_as_uint(x);
    unsigned int r = b + 0x7fffu + ((b >> 16) & 1u);
    return (unsigned short)(r >> 16);
}
__device__ __forceinline__ float lof(unsigned int u) { return __uint_as_float(u << 16); }
__device__ __forceinline__ float hif(unsigned int u) { return __uint_as_float(u & 0xffff0000u); }
__device__ __forceinline__ unsigned int pk2(float a, float b) {
    return (unsigned int)f2b(a) | ((unsigned int)f2b(b) << 16);
}

__device__ __forceinline__ float gelu_exact(float z) {
    return 0.5f * z * (1.0f + erff(z * 0.70710678118654752f));
}

// ---------------------------------------------------------------------------
// CSR build: direct-fill binning (fixed per-bucket capacity, no prefix scan)
// ---------------------------------------------------------------------------
__global__ __launch_bounds__(256) void kb_fill(const int* __restrict__ src,
        const int* __restrict__ dst, int* __restrict__ cursor,
        unsigned int* __restrict__ pairs) {
    __shared__ int cnt[NBUK], base[NBUK], boff[NBUK];
    int t = threadIdx.x;
    for (int i = t; i < NBUK; i += 256) { cnt[i] = 0; boff[i] = 0; }
    __syncthreads();
    int e0 = blockIdx.x * 8192;
    #pragma unroll 4
    for (int i = 0; i < 32; ++i) {
        int e = e0 + i * 256 + t;
        if (e < EE) atomicAdd(&cnt[dst[e] >> 8], 1);
    }
    __syncthreads();
    for (int i = t; i < NBUK; i += 256)
        if (cnt[i]) base[i] = atomicAdd(&cursor[i], cnt[i]);
    __syncthreads();
    #pragma unroll 4
    for (int i = 0; i < 32; ++i) {
        int e = e0 + i * 256 + t;
        if (e < EE) {
            int d = dst[e];
            int b = d >> 8;
            int pos = base[b] + atomicAdd(&boff[b], 1);
            pairs[(size_t)b * CAP + pos] = (unsigned int)src[e]
                                         | ((unsigned int)(d & 255) << 17);
        }
    }
}

__global__ __launch_bounds__(256) void kb_csr(const unsigned int* __restrict__ pairs,
        const int* __restrict__ cursor, int* __restrict__ row_start,
        int* __restrict__ deg, float* __restrict__ invdeg, int* __restrict__ col) {
    __shared__ int ldeg[256];
    __shared__ int lcnt[256];
    __shared__ int colL[CAP];
    int b = blockIdx.x, t = threadIdx.x;
    int e0 = b * CAP;
    int cb = cursor[b];          // edges in this bucket
    ldeg[t] = 0;
    lcnt[t] = 0;
    __syncthreads();
    for (int e = t; e < cb; e += 256) atomicAdd(&ldeg[pairs[e0 + e] >> 17], 1);
    __syncthreads();
    int d = ldeg[t];
    for (int off = 1; off < 256; off <<= 1) {
        int add = (t >= off) ? ldeg[t - off] : 0;
        __syncthreads();
        ldeg[t] += add;
        __syncthreads();
    }
    int n = b * 256 + t;
    if (n < NN) {
        row_start[n] = e0 + ldeg[t] - d;
        deg[n] = d;
        invdeg[n] = 1.0f / fmaxf((float)d, 1.0f);
    }
    __syncthreads();
    for (int e = t; e < cb; e += 256) {
        unsigned int p = pairs[e0 + e];
        int dL = p >> 17;
        int pos = (dL ? ldeg[dL - 1] : 0) + atomicAdd(&lcnt[dL], 1);
        colL[pos] = (int)(p & 0x1FFFFu);
    }
    __syncthreads();
    for (int e = t; e < cb; e += 256) col[e0 + e] = colL[e];   // coalesced
}

// ---------------------------------------------------------------------------
// Mega-pack: xb, A0pack x/zero fill, Wt0, Wt2a, Wt2b, W1b, W2b, biases,
// cursor zero-init.
// ---------------------------------------------------------------------------
#define XB_N  (NN * 32)
#define A0_N  (NN * 64)
#define PACK_TOTAL (XB_N + A0_N + 8192 + 32768 + 32768 + 8192 + 2048 + 64 + 32 + NBUK)
__global__ __launch_bounds__(256) void k_pack_all(const float* __restrict__ x,
        const float* __restrict__ Wl0, const float* __restrict__ Wr0,
        const float* __restrict__ Wl1, const float* __restrict__ Wr1,
        const float* __restrict__ Wl2, const float* __restrict__ Wr2,
        const float* __restrict__ hW1, const float* __restrict__ hW2,
        const float* __restrict__ hb1, const float* __restrict__ hb2,
        unsigned short* __restrict__ xb, unsigned short* __restrict__ A0,
        unsigned short* __restrict__ Wt0, unsigned short* __restrict__ Wt2a,
        unsigned short* __restrict__ Wt2b, unsigned short* __restrict__ W1b,
        unsigned short* __restrict__ W2b, float* __restrict__ bH1,
        float* __restrict__ bH2, int* __restrict__ cursor) {
    int id = blockIdx.x * 256 + threadIdx.x;
    if (id < XB_N) {
        int n = id >> 5, k = id & 31;
        xb[id] = f2b((k < FIN) ? x[n * FIN + k] : 0.0f);
        return;
    }
    id -= XB_N;
    if (id < A0_N) {
        int k = id & 63;
        if (k >= FIN) {   // agg cols 0..19 written by k_agg0
            int n = id >> 6;
            float v = (k >= 32 && k < 32 + FIN) ? x[n * FIN + (k - 32)] : 0.0f;
            A0[id] = f2b(v);
        }
        return;
    }
    id -= A0_N;
    if (id < 8192) {  // Wt0: 128 x 64  [Wl0(20)|0|Wr0(20)|0]
        int c = id >> 6, k = id & 63;
        float v = 0.0f;
        if (k < FIN) v = Wl0[c * FIN + k];
        else if (k >= 32 && k < 32 + FIN) v = Wr0[c * FIN + (k - 32)];
        Wt0[id] = f2b(v);
        return;
    }
    id -= 8192;
    if (id < 32768) {  // layer-1 weights 128 x 256
        int c = id >> 8, k = id & 255;
        Wt2a[id] = f2b((k < HH) ? Wl1[c * HH + k] : Wr1[c * HH + (k - HH)]);
        return;
    }
    id -= 32768;
    if (id < 32768) {  // layer-2 weights
        int c = id >> 8, k = id & 255;
        Wt2b[id] = f2b((k < HH) ? Wl2[c * HH + k] : Wr2[c * HH + (k - HH)]);
        return;
    }
    id -= 32768;
    if (id < 8192) { W1b[id] = f2b(hW1[id]); return; }   // 64 x 128
    id -= 8192;
    if (id < 2048) { W2b[id] = f2b(hW2[id]); return; }   // 32 x 64
    id -= 2048;
    if (id < 64) { bH1[id] = hb1[id]; return; }
    id -= 64;
    if (id < 32) { bH2[id] = hb2[id]; return; }
    id -= 32;
    if (id < NBUK) { cursor[id] = 0; return; }
}

// ---------------------------------------------------------------------------
// Layer-0 aggregation (SEPARATE, high-occupancy): wave = 1 node, 8 edges x
// 8 lanes (uint2), 4 nodes/block, 25k blocks — gathers xb 64 B rows.
// ---------------------------------------------------------------------------
__global__ __launch_bounds__(256) void k_agg0(const uint2* __restrict__ xb2,
        const int* __restrict__ rs, const int* __restrict__ deg,
        const float* __restrict__ inv, const int* __restrict__ col,
        unsigned short* __restrict__ A0) {
    int wid = threadIdx.x >> 6;
    int lane = threadIdx.x & 63;
    int er = lane >> 3;    // edge slot 0..7
    int c8 = lane & 7;     // uint2 chunk within 64 B row
    int n = blockIdx.x * 4 + wid;
    if (n >= NN) return;
    int s = rs[n], d = deg[n];
    float a0 = 0.f, a1 = 0.f, a2 = 0.f, a3 = 0.f;
    for (int j0 = 0; j0 < d; j0 += 8) {
        int j = j0 + er;
        if (j < d) {
            int c = col[s + j];
            uint2 v = xb2[(size_t)c * 8 + c8];
            a0 += lof(v.x); a1 += hif(v.x);
            a2 += lof(v.y); a3 += hif(v.y);
        }
    }
    #pragma unroll
    for (int m = 8; m < 64; m <<= 1) {
        a0 += __shfl_xor(a0, m, 64);
        a1 += __shfl_xor(a1, m, 64);
        a2 += __shfl_xor(a2, m, 64);
        a3 += __shfl_xor(a3, m, 64);
    }
    if (er == 0 && c8 < 5) {   // channels 0..19 only
        float iv = inv[n];
        uint2 o;
        o.x = pk2(a0 * iv, a1 * iv);
        o.y = pk2(a2 * iv, a3 * iv);
        ((uint2*)A0)[(size_t)n * 16 + c8] = o;
    }
}

// ---------------------------------------------------------------------------
// Wide bf16 aggregation (round-3 form): 1 wave per node, lane = 2 channels,
// full 256 B coalesced row reads — at the LLC-bandwidth roofline (~60 us).
// ---------------------------------------------------------------------------
__global__ __launch_bounds__(64) void k_aggb(const unsigned short* __restrict__ hB,
        const int* __restrict__ rs, const int* __restrict__ deg,
        const float* __restrict__ inv, const int* __restrict__ col,
        unsigned short* __restrict__ aggB) {
    int n = blockIdx.x;
    int t = threadIdx.x;
    int s = rs[n], d = deg[n];
    const unsigned int* h32 = (const unsigned int*)hB;
    float a0 = 0.0f, a1 = 0.0f;
    int j = 0;
    for (; j + 3 < d; j += 4) {
        int c0 = col[s + j], c1 = col[s + j + 1];
        int c2 = col[s + j + 2], c3 = col[s + j + 3];
        unsigned int u0 = h32[(size_t)c0 * 64 + t];
        unsigned int u1 = h32[(size_t)c1 * 64 + t];
        unsigned int u2 = h32[(size_t)c2 * 64 + t];
        unsigned int u3 = h32[(size_t)c3 * 64 + t];
        a0 += lof(u0) + lof(u1) + lof(u2) + lof(u3);
        a1 += hif(u0) + hif(u1) + hif(u2) + hif(u3);
    }
    for (; j < d; ++j) {
        unsigned int u = h32[(size_t)col[s + j] * 64 + t];
        a0 += lof(u);
        a1 += hif(u);
    }
    float iv = inv[n];
    ((unsigned int*)aggB)[(size_t)n * 64 + t] = pk2(a0 * iv, a1 * iv);
}

// ---------------------------------------------------------------------------
// bf16 MFMA GEMM with per-block GraphNorm partial stats.
// ---------------------------------------------------------------------------
__global__ __launch_bounds__(256) void k_mm(const unsigned short* __restrict__ A0,
        const unsigned short* __restrict__ A1, int c0, int kChunks, int lda,
        const unsigned short* __restrict__ B, int ldb,
        const float* __restrict__ bias, unsigned short* __restrict__ outB,
        float* __restrict__ psPart, float* __restrict__ pqPart, int M) {
    __shared__ __align__(16) unsigned short As[128 * 40];
    __shared__ __align__(16) unsigned short Bs[128 * 40];
    __shared__ float redS[2][128], redQ[2][128];
    const int tid = threadIdx.x;
    const int m0 = blockIdx.x * 128;
    const int w = tid >> 6, lane = tid & 63;
    const int wr = w >> 1, wc = w & 1;
    const int m16 = lane & 15, q = lane >> 4;

    f32x4 acc[4][4];
    #pragma unroll
    for (int i = 0; i < 4; ++i)
        #pragma unroll
        for (int j = 0; j < 4; ++j) acc[i][j] = (f32x4){0.f, 0.f, 0.f, 0.f};

    for (int chunk = 0; chunk < kChunks; ++chunk) {
        const unsigned short* A = (chunk < c0) ? A0 : A1;
        const int kb = (chunk - ((chunk < c0) ? 0 : c0)) * 32;
        #pragma unroll
        for (int it = 0; it < 2; ++it) {
            int s = tid + it * 256;
            int r = s >> 2, p = s & 3;
            int gm = m0 + r;
            uint4 v = make_uint4(0u, 0u, 0u, 0u);
            if (gm < M) v = *(const uint4*)(A + (size_t)gm * lda + kb + p * 8);
            *(uint4*)&As[r * 40 + p * 8] = v;
        }
        {
            const int kbB = chunk * 32;
            #pragma unroll
            for (int it = 0; it < 2; ++it) {
                int s = tid + it * 256;
                int r = s >> 2, p = s & 3;
                uint4 v = *(const uint4*)(B + (size_t)r * ldb + kbB + p * 8);
                *(uint4*)&Bs[r * 40 + p * 8] = v;
            }
        }
        __syncthreads();
        bf16x8 af[4], bfr[4];
        #pragma unroll
        for (int i = 0; i < 4; ++i)
            af[i] = *(const bf16x8*)&As[(wr * 64 + i * 16 + m16) * 40 + q * 8];
        #pragma unroll
        for (int j = 0; j < 4; ++j)
            bfr[j] = *(const bf16x8*)&Bs[(wc * 64 + j * 16 + m16) * 40 + q * 8];
        #pragma unroll
        for (int i = 0; i < 4; ++i)
            #pragma unroll
            for (int j = 0; j < 4; ++j)
                acc[i][j] = __builtin_amdgcn_mfma_f32_16x16x32_bf16(af[i], bfr[j], acc[i][j], 0, 0, 0);
        __syncthreads();
    }

    float cs[4] = {0.f, 0.f, 0.f, 0.f};
    float cq[4] = {0.f, 0.f, 0.f, 0.f};
    #pragma unroll
    for (int i = 0; i < 4; ++i) {
        int mBase = m0 + wr * 64 + i * 16 + q * 4;
        #pragma unroll
        for (int j = 0; j < 4; ++j) {
            int cc = wc * 64 + j * 16 + m16;
            float bv = bias[cc];
            #pragma unroll
            for (int r = 0; r < 4; ++r) {
                int m = mBase + r;
                float v = (m < M) ? (acc[i][j][r] + bv) : 0.0f;
                if (m < M) outB[(size_t)m * 128 + cc] = f2b(v);
                cs[j] += v;
                cq[j] += v * v;
            }
        }
    }
    #pragma unroll
    for (int msk = 16; msk < 64; msk <<= 1) {
        #pragma unroll
        for (int j = 0; j < 4; ++j) {
            cs[j] += __shfl_xor(cs[j], msk, 64);
            cq[j] += __shfl_xor(cq[j], msk, 64);
        }
    }
    if (q == 0) {
        #pragma unroll
        for (int j = 0; j < 4; ++j) {
            int cc = wc * 64 + j * 16 + m16;
            redS[wr][cc] = cs[j];
            redQ[wr][cc] = cq[j];
        }
    }
    __syncthreads();
    if (tid < 128) {
        psPart[(size_t)blockIdx.x * 128 + tid] = redS[0][tid] + redS[1][tid];
        pqPart[(size_t)blockIdx.x * 128 + tid] = redQ[0][tid] + redQ[1][tid];
    }
}

// ---------------------------------------------------------------------------
// GraphNorm final coeffs: 1024 threads = 8 slices x 128 channels, LDS reduce
// ---------------------------------------------------------------------------
__global__ __launch_bounds__(1024) void k_gn_final(const float* __restrict__ ps,
        const float* __restrict__ pq, const float* __restrict__ gw,
        const float* __restrict__ gb, const float* __restrict__ ga,
        float* __restrict__ cA, float* __restrict__ cB, int nP) {
    __shared__ float shs[8][128], shq[8][128];
    int c = threadIdx.x & 127, sl = threadIdx.x >> 7;
    float s = 0.0f, q = 0.0f;
    for (int b = sl; b < nP; b += 8) {
        s += ps[b * 128 + c];
        q += pq[b * 128 + c];
    }
    shs[sl][c] = s;
    shq[sl][c] = q;
    __syncthreads();
    if (threadIdx.x < 128) {
        float S = 0.0f, Q = 0.0f;
        #pragma unroll
        for (int i = 0; i < 8; ++i) { S += shs[i][c]; Q += shq[i][c]; }
        float mean = S / (float)NN;
        float msq  = Q / (float)NN;
        float a = ga[c];
        float var = msq - mean * mean * a * (2.0f - a);
        float rstd = rsqrtf(var + 1e-5f);
        float A = gw[c] * rstd;
        cA[c] = A;
        cB[c] = gb[c] - a * mean * A;
    }
}

// ---------------------------------------------------------------------------
// GraphNorm apply: affine+GELU, yB (bf16, row-major) -> hB (bf16, row-major)
// ---------------------------------------------------------------------------
__global__ __launch_bounds__(256) void k_gn_apply(const unsigned short* __restrict__ yB,
        const float* __restrict__ cA, const float* __restrict__ cB,
        unsigned short* __restrict__ hB) {
    int i = blockIdx.x * 256 + threadIdx.x;  // uint4 index (8 bf16)
    if (i >= NN * 16) return;
    int g = i & 15;                          // channel group (8 ch)
    uint4 v = ((const uint4*)yB)[i];
    float4 A0 = ((const float4*)cA)[g * 2];
    float4 A1 = ((const float4*)cA)[g * 2 + 1];
    float4 B0 = ((const float4*)cB)[g * 2];
    float4 B1 = ((const float4*)cB)[g * 2 + 1];
    unsigned int o0 = pk2(gelu_exact(lof(v.x) * A0.x + B0.x),
                          gelu_exact(hif(v.x) * A0.y + B0.y));
    unsigned int o1 = pk2(gelu_exact(lof(v.y) * A0.z + B0.z),
                          gelu_exact(hif(v.y) * A0.w + B0.w));
    unsigned int o2 = pk2(gelu_exact(lof(v.z) * A1.x + B1.x),
                          gelu_exact(hif(v.z) * A1.y + B1.y));
    unsigned int o3 = pk2(gelu_exact(lof(v.w) * A1.z + B1.z),
                          gelu_exact(hif(v.w) * A1.w + B1.w));
    ((uint4*)hB)[i] = make_uint4(o0, o1, o2, o3);
}

// ---------------------------------------------------------------------------
// Fused head with layer-2 GraphNorm apply folded into staging.
// ---------------------------------------------------------------------------
__global__ __launch_bounds__(256) void k_headf(const unsigned short* __restrict__ yB,
        const float* __restrict__ cAp, const float* __restrict__ cBp,
        const unsigned short* __restrict__ W1b, const float* __restrict__ b1,
        const unsigned short* __restrict__ W2b, const float* __restrict__ b2,
        const float* __restrict__ W3, const float* __restrict__ b3,
        float* __restrict__ out) {
    __shared__ __align__(16) char pool[23040];
    unsigned short* As  = (unsigned short*)pool;             // 128 x 40
    unsigned short* Bs  = (unsigned short*)(pool + 10240);   // 64 x 40
    unsigned short* As2 = (unsigned short*)pool;             // 128 x 72
    unsigned short* Bs2 = (unsigned short*)(pool + 18432);   // 32 x 72
    const int tid = threadIdx.x;
    const int m0 = blockIdx.x * 128;
    const int w = tid >> 6, lane = tid & 63;
    const int m16 = lane & 15, q = lane >> 4;
    const float4* cA4 = (const float4*)cAp;
    const float4* cB4 = (const float4*)cBp;

    #pragma unroll
    for (int it = 0; it < 8; ++it) {
        int i = tid + it * 256;
        if (i < 2048) Bs2[(i >> 6) * 72 + (i & 63)] = W2b[i];
    }

    f32x4 acc1[2][4];
    #pragma unroll
    for (int i = 0; i < 2; ++i)
        #pragma unroll
        for (int j = 0; j < 4; ++j) acc1[i][j] = (f32x4){0.f, 0.f, 0.f, 0.f};

    for (int chunk = 0; chunk < 4; ++chunk) {
        const int kb = chunk * 32;
        #pragma unroll
        for (int it = 0; it < 2; ++it) {
            int s = tid + it * 256;
            int r = s >> 2, p = s & 3;
            int gm = m0 + r;
            uint4 v = make_uint4(0u, 0u, 0u, 0u);
            if (gm < NN) v = *(const uint4*)(yB + (size_t)gm * 128 + kb + p * 8);
            int cg = chunk * 8 + p * 2;
            float4 Ax = cA4[cg], Ay = cA4[cg + 1];
            float4 Bx = cB4[cg], By = cB4[cg + 1];
            uint4 o;
            o.x = pk2(gelu_exact(lof(v.x) * Ax.x + Bx.x),
                      gelu_exact(hif(v.x) * Ax.y + Bx.y));
            o.y = pk2(gelu_exact(lof(v.y) * Ax.z + Bx.z),
                      gelu_exact(hif(v.y) * Ax.w + Bx.w));
            o.z = pk2(gelu_exact(lof(v.z) * Ay.x + By.x),
                      gelu_exact(hif(v.z) * Ay.y + By.y));
            o.w = pk2(gelu_exact(lof(v.w) * Ay.z + By.z),
                      gelu_exact(hif(v.w) * Ay.w + By.w));
            *(uint4*)&As[r * 40 + p * 8] = o;
        }
        {
            int r = tid >> 2, p = tid & 3;
            uint4 v = *(const uint4*)(W1b + (size_t)r * 128 + kb + p * 8);
            *(uint4*)&Bs[r * 40 + p * 8] = v;
        }
        __syncthreads();
        bf16x8 af[2], bfr[4];
        #pragma unroll
        for (int i = 0; i < 2; ++i)
            af[i] = *(const bf16x8*)&As[(w * 32 + i * 16 + m16) * 40 + q * 8];
        #pragma unroll
        for (int j = 0; j < 4; ++j)
            bfr[j] = *(const bf16x8*)&Bs[(j * 16 + m16) * 40 + q * 8];
        #pragma unroll
        for (int i = 0; i < 2; ++i)
            #pragma unroll
            for (int j = 0; j < 4; ++j)
                acc1[i][j] = __builtin_amdgcn_mfma_f32_16x16x32_bf16(af[i], bfr[j], acc1[i][j], 0, 0, 0);
        __syncthreads();
    }

    {
        float b1v[4];
        #pragma unroll
        for (int j = 0; j < 4; ++j) b1v[j] = b1[j * 16 + m16];
        #pragma unroll
        for (int i = 0; i < 2; ++i) {
            int mloc = w * 32 + i * 16 + q * 4;
            #pragma unroll
            for (int j = 0; j < 4; ++j) {
                int c = j * 16 + m16;
                #pragma unroll
                for (int r = 0; r < 4; ++r)
                    As2[(mloc + r) * 72 + c] = f2b(gelu_exact(acc1[i][j][r] + b1v[j]));
            }
        }
    }
    __syncthreads();

    f32x4 acc2[2][2];
    #pragma unroll
    for (int i = 0; i < 2; ++i)
        #pragma unroll
        for (int j = 0; j < 2; ++j) acc2[i][j] = (f32x4){0.f, 0.f, 0.f, 0.f};
    #pragma unroll
    for (int kc = 0; kc < 2; ++kc) {
        bf16x8 a2[2], bf2[2];
        #pragma unroll
        for (int i = 0; i < 2; ++i)
            a2[i] = *(const bf16x8*)&As2[(w * 32 + i * 16 + m16) * 72 + kc * 32 + q * 8];
        #pragma unroll
        for (int j = 0; j < 2; ++j)
            bf2[j] = *(const bf16x8*)&Bs2[(j * 16 + m16) * 72 + kc * 32 + q * 8];
        #pragma unroll
        for (int i = 0; i < 2; ++i)
            #pragma unroll
            for (int j = 0; j < 2; ++j)
                acc2[i][j] = __builtin_amdgcn_mfma_f32_16x16x32_bf16(a2[i], bf2[j], acc2[i][j], 0, 0, 0);
    }

    float w3a = W3[m16], w3b = W3[16 + m16];
    float b2a = b2[m16], b2b = b2[16 + m16];
    float p[8];
    #pragma unroll
    for (int i = 0; i < 2; ++i)
        #pragma unroll
        for (int r = 0; r < 4; ++r) {
            float za = gelu_exact(acc2[i][0][r] + b2a);
            float zb = gelu_exact(acc2[i][1][r] + b2b);
            p[i * 4 + r] = za * w3a + zb * w3b;
        }
    #pragma unroll
    for (int msk = 1; msk < 16; msk <<= 1)
        #pragma unroll
        for (int k = 0; k < 8; ++k) p[k] += __shfl_xor(p[k], msk, 64);
    if (m16 == 0) {
        float b3v = b3[0];
        #pragma unroll
        for (int i = 0; i < 2; ++i)
            #pragma unroll
            for (int r = 0; r < 4; ++r) {
                int m = m0 + w * 32 + i * 16 + q * 4 + r;
                if (m < NN) out[m] = 1.0f / (1.0f + expf(-(p[i * 4 + r] + b3v)));
            }
    }
}

// ---------------------------------------------------------------------------
// Launch (15 dispatches)
// ---------------------------------------------------------------------------
extern "C" void kernel_launch(void* const* d_in, const int* in_sizes, int n_in,
                              void* d_out, int out_size, void* d_ws, size_t ws_size,
                              hipStream_t stream) {
    const float* x   = (const float*)d_in[0];
    const int*   ei  = (const int*)d_in[1];
    const float* Wl0 = (const float*)d_in[2];
    const float* bl0 = (const float*)d_in[3];
    const float* Wr0 = (const float*)d_in[4];
    const float* gw0 = (const float*)d_in[5];
    const float* gb0 = (const float*)d_in[6];
    const float* ga0 = (const float*)d_in[7];
    const float* Wl1 = (const float*)d_in[8];
    const float* bl1 = (const float*)d_in[9];
    const float* Wr1 = (const float*)d_in[10];
    const float* gw1 = (const float*)d_in[11];
    const float* gb1 = (const float*)d_in[12];
    const float* ga1 = (const float*)d_in[13];
    const float* Wl2 = (const float*)d_in[14];
    const float* bl2 = (const float*)d_in[15];
    const float* Wr2 = (const float*)d_in[16];
    const float* gw2 = (const float*)d_in[17];
    const float* gb2 = (const float*)d_in[18];
    const float* ga2 = (const float*)d_in[19];
    const float* hW1 = (const float*)d_in[20];
    const float* hb1 = (const float*)d_in[21];
    const float* hW2 = (const float*)d_in[22];
    const float* hb2 = (const float*)d_in[23];
    const float* hW3 = (const float*)d_in[24];
    const float* hb3 = (const float*)d_in[25];
    float* out = (float*)d_out;

    size_t off = 0;
    auto carve = [&](size_t bytes) -> void* {
        void* p = (void*)((char*)d_ws + off);
        off += (bytes + 255) & ~(size_t)255;
        return p;
    };
    int*   cursor    = (int*)carve((size_t)NBUK * 4);
    unsigned int* pairs = (unsigned int*)carve((size_t)NBUK * CAP * 4);
    int*   deg       = (int*)carve((size_t)NN * 4);
    int*   row_start = (int*)carve((size_t)NN * 4);
    float* invdeg    = (float*)carve((size_t)NN * 4);
    int*   colarr    = (int*)carve((size_t)NBUK * CAP * 4);
    unsigned short* xb    = (unsigned short*)carve((size_t)NN * 32 * 2);
    unsigned short* Wt0   = (unsigned short*)carve(128 * 64 * 2);
    unsigned short* Wt2a  = (unsigned short*)carve(128 * 256 * 2);
    unsigned short* Wt2b  = (unsigned short*)carve(128 * 256 * 2);
    unsigned short* W1b   = (unsigned short*)carve(64 * 128 * 2);
    unsigned short* W2b   = (unsigned short*)carve(32 * 64 * 2);
    float* biasH1    = (float*)carve(64 * 4);
    float* biasH2    = (float*)carve(32 * 4);
    float* ps        = (float*)carve((size_t)MMB * 128 * 4);
    float* pq        = (float*)carve((size_t)MMB * 128 * 4);
    float* cAall     = (float*)carve(3 * 128 * 4);
    float* cBall     = (float*)carve(3 * 128 * 4);
    unsigned short* A0pack = (unsigned short*)carve((size_t)NN * 64 * 2);
    unsigned short* hB   = (unsigned short*)carve((size_t)NN * HH * 2);
    unsigned short* aggB = (unsigned short*)carve((size_t)NN * HH * 2);
    unsigned short* yB   = (unsigned short*)carve((size_t)NN * HH * 2);
    if (off > ws_size) return;

    const int* src = ei;
    const int* dst = ei + EE;

    // Packing (also zero-inits cursor) + direct-fill CSR build
    k_pack_all<<<(PACK_TOTAL + 255) / 256, 256, 0, stream>>>(
        x, Wl0, Wr0, Wl1, Wr1, Wl2, Wr2, hW1, hW2, hb1, hb2,
        xb, A0pack, Wt0, Wt2a, Wt2b, W1b, W2b, biasH1, biasH2, cursor);
    kb_fill<<<FILLB, 256, 0, stream>>>(src, dst, cursor, pairs);
    kb_csr<<<NBUK, 256, 0, stream>>>(pairs, cursor, row_start, deg, invdeg, colarr);

    // Layer 0: separate high-occupancy gather, then K=64 MFMA GEMM
    k_agg0<<<(NN + 3) / 4, 256, 0, stream>>>((const uint2*)xb, row_start,
                                             deg, invdeg, colarr, A0pack);
    k_mm<<<MMB, 256, 0, stream>>>(A0pack, A0pack, 2, 2, 64, Wt0, 64, bl0, yB, ps, pq, NN);
    k_gn_final<<<1, 1024, 0, stream>>>(ps, pq, gw0, gb0, ga0, cAall + 0, cBall + 0, MMB);
    k_gn_apply<<<(NN * 16 + 255) / 256, 256, 0, stream>>>(yB, cAall + 0, cBall + 0, hB);

    // Layer 1
    k_aggb<<<NN, 64, 0, stream>>>(hB, row_start, deg, invdeg, colarr, aggB);
    k_mm<<<MMB, 256, 0, stream>>>(aggB, hB, 4, 8, 128, Wt2a, 256, bl1, yB, ps, pq, NN);
    k_gn_final<<<1, 1024, 0, stream>>>(ps, pq, gw1, gb1, ga1, cAall + 128, cBall + 128, MMB);
    k_gn_apply<<<(NN * 16 + 255) / 256, 256, 0, stream>>>(yB, cAall + 128, cBall + 128, hB);

    // Layer 2 (apply fused into head)
    k_aggb<<<NN, 64, 0, stream>>>(hB, row_start, deg, invdeg, colarr, aggB);
    k_mm<<<MMB, 256, 0, stream>>>(aggB, hB, 4, 8, 128, Wt2b, 256, bl2, yB, ps, pq, NN);
    k_gn_final<<<1, 1024, 0, stream>>>(ps, pq, gw2, gb2, ga2, cAall + 256, cBall + 256, MMB);

    // Fused head (applies layer-2 GraphNorm+GELU during staging)
    k_headf<<<MMB, 256, 0, stream>>>(yB, cAall + 256, cBall + 256,
                                     W1b, biasH1, W2b, biasH2, hW3, hb3, out);
}